// Round 15
// baseline (804.043 us; speedup 1.0000x reference)
//
#include <hip/hip_runtime.h>

#define EDIM 1024
#define NHEADS 16
#define HDIM 64
#define SEQ 2048
#define BATCH 4
#define MROWS (BATCH * SEQ)   // 8192
#define NQKV (3 * EDIM)       // 3072
#define QKB 2048              // QK buffer row stride (Q cols 0..1023, K 1024..2047)

typedef __attribute__((ext_vector_type(4))) float f32x4;
typedef __attribute__((ext_vector_type(8))) short s16x8;
typedef __attribute__((ext_vector_type(4))) short s16x4;
typedef __attribute__((ext_vector_type(4))) unsigned int u32x4;

#define AS1 __attribute__((address_space(1)))
#define AS3 __attribute__((address_space(3)))
#define GLOAD_LDS16(g, l) __builtin_amdgcn_global_load_lds( \
    (AS1 void*)(void*)(g), (AS3 void*)(void*)(l), 16, 0, 0)

static __device__ __forceinline__ unsigned short f2bf(float f) {
  unsigned int u = __builtin_bit_cast(unsigned int, f);
  u += 0x7fffu + ((u >> 16) & 1u);   // RNE
  return (unsigned short)(u >> 16);
}

static __device__ __forceinline__ float fexp2(float x) {
  float r;
  asm("v_exp_f32 %0, %1" : "=v"(r) : "v"(x));
  return r;
}

static __device__ __forceinline__ unsigned int cvtpk(float a, float b) {
  unsigned int r;
  asm("v_cvt_pk_bf16_f32 %0, %1, %2" : "=v"(r) : "v"(a), "v"(b));
  return r;
}

static __device__ __forceinline__ f32x4 mfma_bf16(s16x8 a, s16x8 b, f32x4 c) {
  return __builtin_amdgcn_mfma_f32_16x16x32_bf16(a, b, c, 0, 0, 0);
}

// counted waitcnt with compile-time literal
template <int N>
static __device__ __forceinline__ void wait_vm() {
  if constexpr (N >= 8)      asm volatile("s_waitcnt lgkmcnt(0) vmcnt(8)" ::: "memory");
  else if constexpr (N == 6) asm volatile("s_waitcnt lgkmcnt(0) vmcnt(6)" ::: "memory");
  else if constexpr (N == 4) asm volatile("s_waitcnt lgkmcnt(0) vmcnt(4)" ::: "memory");
  else if constexpr (N == 3) asm volatile("s_waitcnt lgkmcnt(0) vmcnt(3)" ::: "memory");
  else if constexpr (N == 2) asm volatile("s_waitcnt lgkmcnt(0) vmcnt(2)" ::: "memory");
  else                       asm volatile("s_waitcnt lgkmcnt(0) vmcnt(0)" ::: "memory");
}

// one kernel converts x, w_qkv, w_proj (outputs contiguous in workspace)
__global__ void __launch_bounds__(256) cvt_all(const float* __restrict__ x,
                                               const float* __restrict__ wq,
                                               const float* __restrict__ wp,
                                               unsigned short* __restrict__ out) {
  const int i = blockIdx.x * 256 + threadIdx.x;   // float4 index
  const float* src;
  int j;
  if (i < 2097152) { src = x;  j = i; }
  else if (i < 2883584) { src = wq; j = i - 2097152; }
  else { src = wp; j = i - 2883584; }
  const float4 v = ((const float4*)src)[j];
  ushort4 o;
  o.x = f2bf(v.x); o.y = f2bf(v.y); o.z = f2bf(v.z); o.w = f2bf(v.w);
  ((ushort4*)out)[i] = o;
}

// ---------------------------------------------------------------------------
// 8-phase deep-pipelined GEMM (round-14, verified).
// ---------------------------------------------------------------------------
template <int MODE, int BMP, int BNP>
__global__ void __launch_bounds__(512, 2) gemm8p(const unsigned short* __restrict__ Ap,
                                                 const unsigned short* __restrict__ Bp,
                                                 const float* __restrict__ bias,
                                                 void* __restrict__ Cout,
                                                 int M, int N, int K) {
  extern __shared__ unsigned short lds[];
  constexpr int AHALF = BMP * 4096;   // u16: (BMP*64) rows x 64 cols
  constexpr int BHALF = BNP * 4096;
  constexpr int BBASE = 4 * AHALF;    // A region = 2 buf x 2 half

  const int tid = threadIdx.x;
  const int lane = tid & 63;
  const int wave = tid >> 6;        // 0..7
  const int wr = wave >> 2;         // 0..1  (M half)
  const int wc = wave & 3;          // 0..3  (N quarter)
  const int lr = lane & 15, kg = lane >> 4;

  const int nwg = gridDim.x;        // divisible by 8
  const int q8 = nwg >> 3;
  const int wgid = (blockIdx.x & 7) * q8 + (blockIdx.x >> 3);  // XCD-bijective
  const int NBM = M >> (BMP == 2 ? 8 : 7);
  const long m0 = (long)(wgid % NBM) * (BMP * 128);
  const long n0 = (long)(wgid / NBM) * (BNP * 128);

#define SA(buf, half, kt) do {                                                  \
    _Pragma("unroll")                                                           \
    for (int i_ = 0; i_ < BMP; ++i_) {                                          \
      const int rh_ = i_ * 64 + wave * 8 + (lane >> 3);                         \
      const int ce_ = ((lane & 7) ^ (lane >> 3)) * 8;                           \
      GLOAD_LDS16(Ap + (m0 + (half) * (BMP * 64) + rh_) * K + (kt) * 64 + ce_,  \
                  &lds[(buf) * 2 * AHALF + (half) * AHALF + i_ * 4096 + wave * 512]); \
    } } while (0)
#define SB(buf, half, kt) do {                                                  \
    _Pragma("unroll")                                                           \
    for (int i_ = 0; i_ < BNP; ++i_) {                                          \
      const int rh_ = i_ * 64 + wave * 8 + (lane >> 3);                         \
      const int ce_ = ((lane & 7) ^ (lane >> 3)) * 8;                           \
      GLOAD_LDS16(Bp + (n0 + (half) * (BNP * 64) + rh_) * K + (kt) * 64 + ce_,  \
                  &lds[BBASE + (buf) * 2 * BHALF + (half) * BHALF + i_ * 4096 + wave * 512]); \
    } } while (0)

#define PH_ENTER() do { __builtin_amdgcn_s_barrier();                           \
    asm volatile("s_waitcnt lgkmcnt(0)" ::: "memory");                          \
    __builtin_amdgcn_sched_barrier(0); } while (0)
#define PH_EXIT() __builtin_amdgcn_s_barrier()
#define PH_EXIT_VM() do { wait_vm<2 * BNP>();                                   \
    __builtin_amdgcn_sched_barrier(0);                                          \
    __builtin_amdgcn_s_barrier(); } while (0)
#define PH_EXIT_VM0() do { wait_vm<0>();                                        \
    __builtin_amdgcn_sched_barrier(0);                                          \
    __builtin_amdgcn_s_barrier(); } while (0)

  f32x4 acc[BMP * 4][BNP * 2] = {};
  s16x8 af[2 * BMP][2], bf0[BNP][2], bf1[BNP][2];

  auto LA = [&](int buf, int qm) {
#pragma unroll
    for (int m = 0; m < 2 * BMP; ++m) {
      const int rh = qm * (BMP * 32) + m * 16 + lr;
      const int ro = (buf * 2 + wr) * AHALF + rh * 64;
#pragma unroll
      for (int ks = 0; ks < 2; ++ks)
        af[m][ks] = *(const s16x8*)
            &lds[ro + (((ks * 64 + kg * 16) ^ ((rh & 7) << 4)) >> 1)];
    }
  };
  auto LB = [&](int buf, int qn, s16x8 (&bf)[BNP][2]) {
#pragma unroll
    for (int n = 0; n < BNP; ++n) {
      const int rh = (wc & 1) * (BNP * 32) + qn * (BNP * 16) + n * 16 + lr;
      const int ro = BBASE + (buf * 2 + (wc >> 1)) * BHALF + rh * 64;
#pragma unroll
      for (int ks = 0; ks < 2; ++ks)
        bf[n][ks] = *(const s16x8*)
            &lds[ro + (((ks * 64 + kg * 16) ^ ((rh & 7) << 4)) >> 1)];
    }
  };
  auto MM = [&](int qm, int qn, s16x8 (&bf)[BNP][2]) {
    __builtin_amdgcn_s_setprio(1);
#pragma unroll
    for (int m = 0; m < 2 * BMP; ++m)
#pragma unroll
      for (int n = 0; n < BNP; ++n)
#pragma unroll
        for (int ks = 0; ks < 2; ++ks)
          acc[qm * 2 * BMP + m][qn * BNP + n] =
              mfma_bf16(af[m][ks], bf[n][ks], acc[qm * 2 * BMP + m][qn * BNP + n]);
    __builtin_amdgcn_s_setprio(0);
  };

  const int nk = K >> 6;      // 64-wide K tiles (16)
  const int nit = nk >> 1;    // 8 iterations, 2 K-tiles each

  SB(0, 0, 0); SB(0, 1, 0);
  SA(0, 0, 0); SA(0, 1, 0);
  SB(1, 0, 1); SB(1, 1, 1);
  wait_vm<2 * BNP>();
  __builtin_amdgcn_sched_barrier(0);
  __builtin_amdgcn_s_barrier();
  __builtin_amdgcn_sched_barrier(0);

  for (int it = 0; it < nit; ++it) {
    const int ta = 2 * it, tb = 2 * it + 1;
    LA(0, 0); LB(0, 0, bf0);
    SA(1, 0, tb);
    PH_ENTER(); MM(0, 0, bf0); PH_EXIT();
    LB(0, 1, bf1);
    SA(1, 1, tb);
    PH_ENTER(); MM(0, 1, bf1); PH_EXIT();
    LA(0, 1);
    if (ta + 2 < nk) SB(0, 0, ta + 2);
    PH_ENTER(); MM(1, 0, bf0); PH_EXIT();
    if (ta + 2 < nk) SB(0, 1, ta + 2);
    PH_ENTER(); MM(1, 1, bf1);
    if (it + 1 < nit) { PH_EXIT_VM(); } else { PH_EXIT_VM0(); }
    LA(1, 0); LB(1, 0, bf0);
    if (ta + 2 < nk) SA(0, 0, ta + 2);
    PH_ENTER(); MM(0, 0, bf0); PH_EXIT();
    LB(1, 1, bf1);
    if (ta + 2 < nk) SA(0, 1, ta + 2);
    PH_ENTER(); MM(0, 1, bf1); PH_EXIT();
    LA(1, 1);
    if (tb + 2 < nk) SB(1, 0, tb + 2);
    PH_ENTER(); MM(1, 0, bf0); PH_EXIT();
    if (tb + 2 < nk) SB(1, 1, tb + 2);
    PH_ENTER(); MM(1, 1, bf1); PH_EXIT_VM();
  }

#pragma unroll
  for (int nt = 0; nt < BNP * 2; ++nt) {
    const long col = n0 + wc * (BNP * 32) + nt * 16 + lr;
    const float bv = (MODE == 2) ? 0.f : bias[col];
#pragma unroll
    for (int mt = 0; mt < BMP * 4; ++mt) {
#pragma unroll
      for (int r = 0; r < 4; ++r) {
        const long row = m0 + wr * (BMP * 64) + mt * 16 + kg * 4 + r;
        if (MODE == 0) {
          float v = acc[mt][nt][r] + bv;
          if (col < EDIM) v *= 0.18033688011112042f;  // 0.125 * log2(e)
          ((unsigned short*)Cout)[row * QKB + col] = f2bf(v);
        } else if (MODE == 1) {
          ((float*)Cout)[row * N + col] = acc[mt][nt][r] + bv;
        } else {
          const float v = acc[mt][nt][r] + bias[row];
          ((unsigned short*)Cout)[((col >> 11) * 1024 + row) * (long)2048 +
                                  (col & 2047)] = f2bf(v);
        }
      }
    }
  }
#undef SA
#undef SB
#undef PH_ENTER
#undef PH_EXIT
#undef PH_EXIT_VM
#undef PH_EXIT_VM0
}

// ---------------------------------------------------------------------------
// Flash attention — r14 base + softmax-lags-QK^T software pipeline.
// Iteration t: stage(t+2) [lead 2]; QK(t)->st_cur (MFMA issue, results not
// consumed this iter); softmax+PV(t-1, st_prev). Slot safety: stage(t+2)
// overwrites tile t-2, last read (PV) at iter t-1 -> barrier-separated; all
// same-iter reads hit slots t&3 and (t-1)&3, both != (t+2)&3.
// Two named st arrays (A/B), 2-iter unrolled pairing (no runtime reg index).
// ---------------------------------------------------------------------------
__global__ void __launch_bounds__(512, 4) attn_fwd(const unsigned short* __restrict__ qk,
                                                   const unsigned short* __restrict__ vT,
                                                   unsigned short* __restrict__ attout) {
  const int L = blockIdx.x;
  const int bh = (L & 7) * 8 + (L >> 6);
  const int qt = (L >> 3) & 7;
  const int b = bh >> 4, h = bh & 15;
  const int q0 = qt * 256;
  const int tid = threadIdx.x, lane = tid & 63, wave = tid >> 6;  // wave 0..7
  const int lr = lane & 15, kg = lane >> 4;

  __shared__ unsigned short Ks[4][4096];   // [slot][k 64][d 64] swizzled
  __shared__ unsigned short Vs[4][4096];   // [slot][d 64][kv 64] swizzled

  const long rowbase = (long)b * SEQ;

#define ASTAGE(slot, kv0) do {                                                  \
    const int row_ = wave * 8 + (lane >> 3);                                    \
    const int col_ = ((lane & 7) ^ (lane >> 3)) << 3;                           \
    GLOAD_LDS16(qk + (rowbase + (kv0) + row_) * QKB + EDIM + h * HDIM + col_,   \
                &Ks[slot][wave * 512]);                                         \
    GLOAD_LDS16(vT + ((long)bh * HDIM + row_) * SEQ + (kv0) + col_,             \
                &Vs[slot][wave * 512]);                                         \
  } while (0)

  s16x8 qf[2][2];
#pragma unroll
  for (int qs = 0; qs < 2; ++qs) {
    const unsigned short* qp =
        qk + (rowbase + q0 + wave * 32 + qs * 16 + lr) * QKB + h * HDIM + kg * 8;
    qf[qs][0] = *(const s16x8*)qp;
    qf[qs][1] = *(const s16x8*)(qp + 32);
  }

  f32x4 l_part[2] = {{0.f, 0.f, 0.f, 0.f}, {0.f, 0.f, 0.f, 0.f}};
  f32x4 o_acc[2][4] = {};
  f32x4 stA[2][4], stB[2][4];

  // QK^T of tile t into st (MFMA issue; consumed next iteration)
  auto QKT = [&](int t, f32x4 (&st)[2][4]) {
    const unsigned short* Kb = Ks[t & 3];
    __builtin_amdgcn_s_setprio(1);
#pragma unroll
    for (int ct = 0; ct < 4; ++ct) {
      const int rb = (ct * 16 + lr) * 128;
      const int sw = (lr & 7) << 4;
      const s16x8 k0 = *(const s16x8*)&Kb[(rb + ((kg * 16) ^ sw)) >> 1];
      const s16x8 k1 = *(const s16x8*)&Kb[(rb + ((64 + kg * 16) ^ sw)) >> 1];
#pragma unroll
      for (int qs = 0; qs < 2; ++qs) {
        f32x4 a = {};
        a = mfma_bf16(k0, qf[qs][0], a);
        a = mfma_bf16(k1, qf[qs][1], a);
        st[qs][ct] = a;
      }
    }
    __builtin_amdgcn_s_setprio(0);
  };

  // softmax + PV of tile t from st (independent of the QK just issued)
  auto SMPV = [&](int t, const f32x4 (&st)[2][4]) {
    const unsigned short* Vb = Vs[t & 3];
    unsigned int pk[2][4][2];
#pragma unroll
    for (int qs = 0; qs < 2; ++qs) {
      f32x4 rv = {0.f, 0.f, 0.f, 0.f};
#pragma unroll
      for (int ct = 0; ct < 4; ++ct) {
        f32x4 p;
#pragma unroll
        for (int r = 0; r < 4; ++r) p[r] = fexp2(st[qs][ct][r]);
        rv += p;
        pk[qs][ct][0] = cvtpk(p[0], p[1]);
        pk[qs][ct][1] = cvtpk(p[2], p[3]);
      }
      l_part[qs] += rv;
    }
#pragma unroll
    for (int kc = 0; kc < 2; ++kc) {
      s16x8 pa[2];
#pragma unroll
      for (int qs = 0; qs < 2; ++qs) {
        u32x4 wv = {pk[qs][2 * kc][0], pk[qs][2 * kc][1],
                    pk[qs][2 * kc + 1][0], pk[qs][2 * kc + 1][1]};
        pa[qs] = __builtin_bit_cast(s16x8, wv);
      }
      __builtin_amdgcn_s_setprio(1);
#pragma unroll
      for (int dt = 0; dt < 4; ++dt) {
        const int rb = (dt * 16 + lr) * 128;
        const int c0 = (64 * kc + 8 * kg) ^ ((lr & 7) << 4);
        const s16x4 v0 = *(const s16x4*)&Vb[(rb + c0) >> 1];
        const s16x4 v1 = *(const s16x4*)&Vb[(rb + (c0 ^ 32)) >> 1];
        const s16x8 vf = __builtin_shufflevector(v0, v1, 0, 1, 2, 3, 4, 5, 6, 7);
#pragma unroll
        for (int qs = 0; qs < 2; ++qs)
          o_acc[qs][dt] = mfma_bf16(pa[qs], vf, o_acc[qs][dt]);
      }
      __builtin_amdgcn_s_setprio(0);
    }
  };

#define BAR() do { __builtin_amdgcn_s_barrier();                                \
    __builtin_amdgcn_sched_barrier(0); } while (0)

  // prologue: tiles 0,1 staged; tile 0 landed
  ASTAGE(0, 0); ASTAGE(1, 64);
  wait_vm<2>();
  __builtin_amdgcn_sched_barrier(0);
  BAR();

  // iter 0: no previous tile
  ASTAGE(2, 128);
  QKT(0, stA);
  wait_vm<2>(); BAR();

  // pairs (1,2),(3,4),...,(29,30)
  for (int t = 1; t <= 29; t += 2) {
    ASTAGE((t + 2) & 3, (t + 2) * 64);
    QKT(t, stB);
    SMPV(t - 1, stA);
    wait_vm<2>(); BAR();

    if (t + 3 < 32) {
      ASTAGE((t + 3) & 3, (t + 3) * 64);
      QKT(t + 1, stA);
      SMPV(t, stB);
      wait_vm<2>(); BAR();
    } else {
      QKT(t + 1, stA);
      SMPV(t, stB);
      wait_vm<0>(); BAR();
    }
  }

  // iter 31 + drain
  QKT(31, stB);
  SMPV(30, stA);
  SMPV(31, stB);

#pragma unroll
  for (int qs = 0; qs < 2; ++qs) {
    float rs = (l_part[qs][0] + l_part[qs][1]) + (l_part[qs][2] + l_part[qs][3]);
    rs += __shfl_xor(rs, 16, 64);
    rs += __shfl_xor(rs, 32, 64);
#pragma unroll
    for (int r = 0; r < 4; ++r) {
      const float lq = __shfl(rs, kg * 4 + r, 64);
      const float inv = 1.0f / lq;
      const long row = rowbase + q0 + wave * 32 + qs * 16 + kg * 4 + r;
#pragma unroll
      for (int dt = 0; dt < 4; ++dt)
        attout[row * EDIM + h * HDIM + dt * 16 + lr] = f2bf(o_acc[qs][dt][r] * inv);
    }
  }
#undef ASTAGE
#undef BAR
}

extern "C" void kernel_launch(void* const* d_in, const int* in_sizes, int n_in,
                              void* d_out, int out_size, void* d_ws, size_t ws_size,
                              hipStream_t stream) {
  const float* x      = (const float*)d_in[0];
  const float* w_qkv  = (const float*)d_in[1];
  const float* b_qkv  = (const float*)d_in[2];
  const float* w_proj = (const float*)d_in[3];
  const float* b_proj = (const float*)d_in[4];

  unsigned short* xb   = (unsigned short*)d_ws;              // 8.39M elems
  unsigned short* wqb  = xb   + (size_t)MROWS * EDIM;        // 3.15M
  unsigned short* wpb  = wqb  + (size_t)NQKV * EDIM;         // 1.05M
  unsigned short* qkb  = wpb  + (size_t)EDIM * EDIM;         // 16.8M ([8192][2048])
  unsigned short* attb = qkb  + (size_t)MROWS * QKB;         // 8.39M
  unsigned short* vTb  = attb + (size_t)MROWS * EDIM;        // 8.39M ([1024][8192])

  const int sh22 = 131072;  // (2+2) x 32KB
  const int sh12 = 98304;   // (1+2) x 32KB
  const int sh21 = 98304;   // (2+1) x 32KB
  hipFuncSetAttribute((const void*)gemm8p<0, 2, 2>,
                      hipFuncAttributeMaxDynamicSharedMemorySize, sh22);
  hipFuncSetAttribute((const void*)gemm8p<2, 1, 2>,
                      hipFuncAttributeMaxDynamicSharedMemorySize, sh12);
  hipFuncSetAttribute((const void*)gemm8p<1, 2, 1>,
                      hipFuncAttributeMaxDynamicSharedMemorySize, sh21);

  cvt_all<<<12288, 256, 0, stream>>>(x, w_qkv, w_proj, xb);

  // QK projection: [8192][2048] (Q pre-scaled into log2 domain). 256 wgs.
  gemm8p<0, 2, 2><<<(MROWS / 256) * (QKB / 256), 512, sh22, stream>>>(
      xb, wqb, b_qkv, qkb, MROWS, QKB, EDIM);

  // V^T directly (swapped operands -> scattered bf16 store). 128x256 tile.
  gemm8p<2, 1, 2><<<(EDIM / 128) * (MROWS / 256), 512, sh12, stream>>>(
      wqb + (size_t)2048 * EDIM, xb, b_qkv + 2048, vTb, EDIM, MROWS, EDIM);

  attn_fwd<<<512, 512, 0, stream>>>(qkb, vTb, attb);

  // proj: 256x128 tile.
  gemm8p<1, 2, 1><<<(MROWS / 256) * (EDIM / 128), 512, sh21, stream>>>(
      attb, wpb, b_proj, d_out, MROWS, EDIM, EDIM);
}

// Round 16
// 559.978 us; speedup vs baseline: 1.4358x; 1.4358x over previous
//
#include <hip/hip_runtime.h>

#define EDIM 1024
#define NHEADS 16
#define HDIM 64
#define SEQ 2048
#define BATCH 4
#define MROWS (BATCH * SEQ)   // 8192
#define NQKV (3 * EDIM)       // 3072
#define QKB 2048              // QK buffer row stride (Q cols 0..1023, K 1024..2047)

typedef __attribute__((ext_vector_type(4))) float f32x4;
typedef __attribute__((ext_vector_type(8))) short s16x8;
typedef __attribute__((ext_vector_type(4))) short s16x4;
typedef __attribute__((ext_vector_type(4))) unsigned int u32x4;

#define AS1 __attribute__((address_space(1)))
#define AS3 __attribute__((address_space(3)))
#define GLOAD_LDS16(g, l) __builtin_amdgcn_global_load_lds( \
    (AS1 void*)(void*)(g), (AS3 void*)(void*)(l), 16, 0, 0)

static __device__ __forceinline__ unsigned short f2bf(float f) {
  unsigned int u = __builtin_bit_cast(unsigned int, f);
  u += 0x7fffu + ((u >> 16) & 1u);   // RNE
  return (unsigned short)(u >> 16);
}

static __device__ __forceinline__ float fexp2(float x) {
  float r;
  asm("v_exp_f32 %0, %1" : "=v"(r) : "v"(x));
  return r;
}

static __device__ __forceinline__ unsigned int cvtpk(float a, float b) {
  unsigned int r;
  asm("v_cvt_pk_bf16_f32 %0, %1, %2" : "=v"(r) : "v"(a), "v"(b));
  return r;
}

static __device__ __forceinline__ f32x4 mfma_bf16(s16x8 a, s16x8 b, f32x4 c) {
  return __builtin_amdgcn_mfma_f32_16x16x32_bf16(a, b, c, 0, 0, 0);
}

// counted waitcnt with compile-time literal
template <int N>
static __device__ __forceinline__ void wait_vm() {
  if constexpr (N >= 8)      asm volatile("s_waitcnt lgkmcnt(0) vmcnt(8)" ::: "memory");
  else if constexpr (N == 6) asm volatile("s_waitcnt lgkmcnt(0) vmcnt(6)" ::: "memory");
  else if constexpr (N == 4) asm volatile("s_waitcnt lgkmcnt(0) vmcnt(4)" ::: "memory");
  else if constexpr (N == 3) asm volatile("s_waitcnt lgkmcnt(0) vmcnt(3)" ::: "memory");
  else if constexpr (N == 2) asm volatile("s_waitcnt lgkmcnt(0) vmcnt(2)" ::: "memory");
  else                       asm volatile("s_waitcnt lgkmcnt(0) vmcnt(0)" ::: "memory");
}

// one kernel converts x, w_qkv, w_proj (outputs contiguous in workspace)
__global__ void __launch_bounds__(256) cvt_all(const float* __restrict__ x,
                                               const float* __restrict__ wq,
                                               const float* __restrict__ wp,
                                               unsigned short* __restrict__ out) {
  const int i = blockIdx.x * 256 + threadIdx.x;   // float4 index
  const float* src;
  int j;
  if (i < 2097152) { src = x;  j = i; }
  else if (i < 2883584) { src = wq; j = i - 2097152; }
  else { src = wp; j = i - 2883584; }
  const float4 v = ((const float4*)src)[j];
  ushort4 o;
  o.x = f2bf(v.x); o.y = f2bf(v.y); o.z = f2bf(v.z); o.w = f2bf(v.w);
  ((ushort4*)out)[i] = o;
}

// ---------------------------------------------------------------------------
// 8-phase deep-pipelined GEMM (round-14, verified).
// ---------------------------------------------------------------------------
template <int MODE, int BMP, int BNP>
__global__ void __launch_bounds__(512, 2) gemm8p(const unsigned short* __restrict__ Ap,
                                                 const unsigned short* __restrict__ Bp,
                                                 const float* __restrict__ bias,
                                                 void* __restrict__ Cout,
                                                 int M, int N, int K) {
  extern __shared__ unsigned short lds[];
  constexpr int AHALF = BMP * 4096;   // u16: (BMP*64) rows x 64 cols
  constexpr int BHALF = BNP * 4096;
  constexpr int BBASE = 4 * AHALF;    // A region = 2 buf x 2 half

  const int tid = threadIdx.x;
  const int lane = tid & 63;
  const int wave = tid >> 6;        // 0..7
  const int wr = wave >> 2;         // 0..1  (M half)
  const int wc = wave & 3;          // 0..3  (N quarter)
  const int lr = lane & 15, kg = lane >> 4;

  const int nwg = gridDim.x;        // divisible by 8
  const int q8 = nwg >> 3;
  const int wgid = (blockIdx.x & 7) * q8 + (blockIdx.x >> 3);  // XCD-bijective
  const int NBM = M >> (BMP == 2 ? 8 : 7);
  const long m0 = (long)(wgid % NBM) * (BMP * 128);
  const long n0 = (long)(wgid / NBM) * (BNP * 128);

#define SA(buf, half, kt) do {                                                  \
    _Pragma("unroll")                                                           \
    for (int i_ = 0; i_ < BMP; ++i_) {                                          \
      const int rh_ = i_ * 64 + wave * 8 + (lane >> 3);                         \
      const int ce_ = ((lane & 7) ^ (lane >> 3)) * 8;                           \
      GLOAD_LDS16(Ap + (m0 + (half) * (BMP * 64) + rh_) * K + (kt) * 64 + ce_,  \
                  &lds[(buf) * 2 * AHALF + (half) * AHALF + i_ * 4096 + wave * 512]); \
    } } while (0)
#define SB(buf, half, kt) do {                                                  \
    _Pragma("unroll")                                                           \
    for (int i_ = 0; i_ < BNP; ++i_) {                                          \
      const int rh_ = i_ * 64 + wave * 8 + (lane >> 3);                         \
      const int ce_ = ((lane & 7) ^ (lane >> 3)) * 8;                           \
      GLOAD_LDS16(Bp + (n0 + (half) * (BNP * 64) + rh_) * K + (kt) * 64 + ce_,  \
                  &lds[BBASE + (buf) * 2 * BHALF + (half) * BHALF + i_ * 4096 + wave * 512]); \
    } } while (0)

#define PH_ENTER() do { __builtin_amdgcn_s_barrier();                           \
    asm volatile("s_waitcnt lgkmcnt(0)" ::: "memory");                          \
    __builtin_amdgcn_sched_barrier(0); } while (0)
#define PH_EXIT() __builtin_amdgcn_s_barrier()
#define PH_EXIT_VM() do { wait_vm<2 * BNP>();                                   \
    __builtin_amdgcn_sched_barrier(0);                                          \
    __builtin_amdgcn_s_barrier(); } while (0)
#define PH_EXIT_VM0() do { wait_vm<0>();                                        \
    __builtin_amdgcn_sched_barrier(0);                                          \
    __builtin_amdgcn_s_barrier(); } while (0)

  f32x4 acc[BMP * 4][BNP * 2] = {};
  s16x8 af[2 * BMP][2], bf0[BNP][2], bf1[BNP][2];

  auto LA = [&](int buf, int qm) {
#pragma unroll
    for (int m = 0; m < 2 * BMP; ++m) {
      const int rh = qm * (BMP * 32) + m * 16 + lr;
      const int ro = (buf * 2 + wr) * AHALF + rh * 64;
#pragma unroll
      for (int ks = 0; ks < 2; ++ks)
        af[m][ks] = *(const s16x8*)
            &lds[ro + (((ks * 64 + kg * 16) ^ ((rh & 7) << 4)) >> 1)];
    }
  };
  auto LB = [&](int buf, int qn, s16x8 (&bf)[BNP][2]) {
#pragma unroll
    for (int n = 0; n < BNP; ++n) {
      const int rh = (wc & 1) * (BNP * 32) + qn * (BNP * 16) + n * 16 + lr;
      const int ro = BBASE + (buf * 2 + (wc >> 1)) * BHALF + rh * 64;
#pragma unroll
      for (int ks = 0; ks < 2; ++ks)
        bf[n][ks] = *(const s16x8*)
            &lds[ro + (((ks * 64 + kg * 16) ^ ((rh & 7) << 4)) >> 1)];
    }
  };
  auto MM = [&](int qm, int qn, s16x8 (&bf)[BNP][2]) {
    __builtin_amdgcn_s_setprio(1);
#pragma unroll
    for (int m = 0; m < 2 * BMP; ++m)
#pragma unroll
      for (int n = 0; n < BNP; ++n)
#pragma unroll
        for (int ks = 0; ks < 2; ++ks)
          acc[qm * 2 * BMP + m][qn * BNP + n] =
              mfma_bf16(af[m][ks], bf[n][ks], acc[qm * 2 * BMP + m][qn * BNP + n]);
    __builtin_amdgcn_s_setprio(0);
  };

  const int nk = K >> 6;      // 64-wide K tiles (16)
  const int nit = nk >> 1;    // 8 iterations, 2 K-tiles each

  SB(0, 0, 0); SB(0, 1, 0);
  SA(0, 0, 0); SA(0, 1, 0);
  SB(1, 0, 1); SB(1, 1, 1);
  wait_vm<2 * BNP>();
  __builtin_amdgcn_sched_barrier(0);
  __builtin_amdgcn_s_barrier();
  __builtin_amdgcn_sched_barrier(0);

  for (int it = 0; it < nit; ++it) {
    const int ta = 2 * it, tb = 2 * it + 1;
    LA(0, 0); LB(0, 0, bf0);
    SA(1, 0, tb);
    PH_ENTER(); MM(0, 0, bf0); PH_EXIT();
    LB(0, 1, bf1);
    SA(1, 1, tb);
    PH_ENTER(); MM(0, 1, bf1); PH_EXIT();
    LA(0, 1);
    if (ta + 2 < nk) SB(0, 0, ta + 2);
    PH_ENTER(); MM(1, 0, bf0); PH_EXIT();
    if (ta + 2 < nk) SB(0, 1, ta + 2);
    PH_ENTER(); MM(1, 1, bf1);
    if (it + 1 < nit) { PH_EXIT_VM(); } else { PH_EXIT_VM0(); }
    LA(1, 0); LB(1, 0, bf0);
    if (ta + 2 < nk) SA(0, 0, ta + 2);
    PH_ENTER(); MM(0, 0, bf0); PH_EXIT();
    LB(1, 1, bf1);
    if (ta + 2 < nk) SA(0, 1, ta + 2);
    PH_ENTER(); MM(0, 1, bf1); PH_EXIT();
    LA(1, 1);
    if (tb + 2 < nk) SB(1, 0, tb + 2);
    PH_ENTER(); MM(1, 0, bf0); PH_EXIT();
    if (tb + 2 < nk) SB(1, 1, tb + 2);
    PH_ENTER(); MM(1, 1, bf1); PH_EXIT_VM();
  }

#pragma unroll
  for (int nt = 0; nt < BNP * 2; ++nt) {
    const long col = n0 + wc * (BNP * 32) + nt * 16 + lr;
    const float bv = (MODE == 2) ? 0.f : bias[col];
#pragma unroll
    for (int mt = 0; mt < BMP * 4; ++mt) {
#pragma unroll
      for (int r = 0; r < 4; ++r) {
        const long row = m0 + wr * (BMP * 64) + mt * 16 + kg * 4 + r;
        if (MODE == 0) {
          float v = acc[mt][nt][r] + bv;
          if (col < EDIM) v *= 0.18033688011112042f;  // 0.125 * log2(e)
          ((unsigned short*)Cout)[row * QKB + col] = f2bf(v);
        } else if (MODE == 1) {
          ((float*)Cout)[row * N + col] = acc[mt][nt][r] + bv;
        } else {
          const float v = acc[mt][nt][r] + bias[row];
          ((unsigned short*)Cout)[((col >> 11) * 1024 + row) * (long)2048 +
                                  (col & 2047)] = f2bf(v);
        }
      }
    }
  }
#undef SA
#undef SB
#undef PH_ENTER
#undef PH_EXIT
#undef PH_EXIT_VM
#undef PH_EXIT_VM0
}

// ---------------------------------------------------------------------------
// Flash attention — softmax-lags-QK^T pipeline, MACRO-inlined (r15's lambda
// version put stA/stB in scratch: FETCH 27.7MB -> 1.1GB. Macros keep the
// arrays SROA-able: constant indices only, no reference params).
// Same sync/slots as r15 (validated): stage lead 2, wait_vm<2> steady.
// ---------------------------------------------------------------------------
__global__ void __launch_bounds__(512, 4) attn_fwd(const unsigned short* __restrict__ qk,
                                                   const unsigned short* __restrict__ vT,
                                                   unsigned short* __restrict__ attout) {
  const int L = blockIdx.x;
  const int bh = (L & 7) * 8 + (L >> 6);
  const int qt = (L >> 3) & 7;
  const int b = bh >> 4, h = bh & 15;
  const int q0 = qt * 256;
  const int tid = threadIdx.x, lane = tid & 63, wave = tid >> 6;  // wave 0..7
  const int lr = lane & 15, kg = lane >> 4;

  __shared__ unsigned short Ks[4][4096];   // [slot][k 64][d 64] swizzled
  __shared__ unsigned short Vs[4][4096];   // [slot][d 64][kv 64] swizzled

  const long rowbase = (long)b * SEQ;

#define ASTAGE(slot, kv0) do {                                                  \
    const int row_ = wave * 8 + (lane >> 3);                                    \
    const int col_ = ((lane & 7) ^ (lane >> 3)) << 3;                           \
    GLOAD_LDS16(qk + (rowbase + (kv0) + row_) * QKB + EDIM + h * HDIM + col_,   \
                &Ks[slot][wave * 512]);                                         \
    GLOAD_LDS16(vT + ((long)bh * HDIM + row_) * SEQ + (kv0) + col_,             \
                &Vs[slot][wave * 512]);                                         \
  } while (0)

  // QK^T of tile T into ST (plain macro: ST stays register-allocated)
#define QKT_M(T, ST) do {                                                       \
    const unsigned short* Kb_ = Ks[(T) & 3];                                    \
    __builtin_amdgcn_s_setprio(1);                                              \
    _Pragma("unroll")                                                           \
    for (int ct = 0; ct < 4; ++ct) {                                            \
      const int rb_ = (ct * 16 + lr) * 128;                                     \
      const int sw_ = (lr & 7) << 4;                                            \
      const s16x8 k0_ = *(const s16x8*)&Kb_[(rb_ + ((kg * 16) ^ sw_)) >> 1];    \
      const s16x8 k1_ = *(const s16x8*)&Kb_[(rb_ + ((64 + kg * 16) ^ sw_)) >> 1];\
      _Pragma("unroll")                                                         \
      for (int qs = 0; qs < 2; ++qs) {                                          \
        f32x4 a_ = {};                                                          \
        a_ = mfma_bf16(k0_, qf[qs][0], a_);                                     \
        a_ = mfma_bf16(k1_, qf[qs][1], a_);                                     \
        ST[qs][ct] = a_;                                                        \
      }                                                                         \
    }                                                                           \
    __builtin_amdgcn_s_setprio(0);                                              \
  } while (0)

  // softmax + PV of tile T from ST
#define SMPV_M(T, ST) do {                                                      \
    const unsigned short* Vb_ = Vs[(T) & 3];                                    \
    unsigned int pk_[2][4][2];                                                  \
    _Pragma("unroll")                                                           \
    for (int qs = 0; qs < 2; ++qs) {                                            \
      f32x4 rv_ = {0.f, 0.f, 0.f, 0.f};                                         \
      _Pragma("unroll")                                                         \
      for (int ct = 0; ct < 4; ++ct) {                                          \
        f32x4 p_;                                                               \
        _Pragma("unroll")                                                       \
        for (int r = 0; r < 4; ++r) p_[r] = fexp2(ST[qs][ct][r]);               \
        rv_ += p_;                                                              \
        pk_[qs][ct][0] = cvtpk(p_[0], p_[1]);                                   \
        pk_[qs][ct][1] = cvtpk(p_[2], p_[3]);                                   \
      }                                                                         \
      l_part[qs] += rv_;                                                        \
    }                                                                           \
    _Pragma("unroll")                                                           \
    for (int kc = 0; kc < 2; ++kc) {                                            \
      s16x8 pa_[2];                                                             \
      _Pragma("unroll")                                                         \
      for (int qs = 0; qs < 2; ++qs) {                                          \
        u32x4 wv_ = {pk_[qs][2 * kc][0], pk_[qs][2 * kc][1],                    \
                     pk_[qs][2 * kc + 1][0], pk_[qs][2 * kc + 1][1]};           \
        pa_[qs] = __builtin_bit_cast(s16x8, wv_);                               \
      }                                                                         \
      __builtin_amdgcn_s_setprio(1);                                            \
      _Pragma("unroll")                                                         \
      for (int dt = 0; dt < 4; ++dt) {                                          \
        const int rb_ = (dt * 16 + lr) * 128;                                   \
        const int c0_ = (64 * kc + 8 * kg) ^ ((lr & 7) << 4);                   \
        const s16x4 v0_ = *(const s16x4*)&Vb_[(rb_ + c0_) >> 1];                \
        const s16x4 v1_ = *(const s16x4*)&Vb_[(rb_ + (c0_ ^ 32)) >> 1];         \
        const s16x8 vf_ = __builtin_shufflevector(v0_, v1_, 0, 1, 2, 3, 4, 5, 6, 7); \
        _Pragma("unroll")                                                       \
        for (int qs = 0; qs < 2; ++qs)                                          \
          o_acc[qs][dt] = mfma_bf16(pa_[qs], vf_, o_acc[qs][dt]);               \
      }                                                                         \
      __builtin_amdgcn_s_setprio(0);                                            \
    }                                                                           \
  } while (0)

#define BAR() do { __builtin_amdgcn_s_barrier();                                \
    __builtin_amdgcn_sched_barrier(0); } while (0)

  s16x8 qf[2][2];
#pragma unroll
  for (int qs = 0; qs < 2; ++qs) {
    const unsigned short* qp =
        qk + (rowbase + q0 + wave * 32 + qs * 16 + lr) * QKB + h * HDIM + kg * 8;
    qf[qs][0] = *(const s16x8*)qp;
    qf[qs][1] = *(const s16x8*)(qp + 32);
  }

  f32x4 l_part[2] = {{0.f, 0.f, 0.f, 0.f}, {0.f, 0.f, 0.f, 0.f}};
  f32x4 o_acc[2][4] = {};
  f32x4 stA[2][4], stB[2][4];

  // prologue: tiles 0,1 staged; tile 0 landed
  ASTAGE(0, 0); ASTAGE(1, 64);
  wait_vm<2>();
  __builtin_amdgcn_sched_barrier(0);
  BAR();

  // iter 0: no previous tile
  ASTAGE(2, 128);
  QKT_M(0, stA);
  wait_vm<2>(); BAR();

  // pairs (1,2),(3,4),...,(29,30)
  for (int t = 1; t <= 29; t += 2) {
    ASTAGE((t + 2) & 3, (t + 2) * 64);
    QKT_M(t, stB);
    SMPV_M(t - 1, stA);
    wait_vm<2>(); BAR();

    if (t + 3 < 32) {
      ASTAGE((t + 3) & 3, (t + 3) * 64);
      QKT_M(t + 1, stA);
      SMPV_M(t, stB);
      wait_vm<2>(); BAR();
    } else {
      QKT_M(t + 1, stA);
      SMPV_M(t, stB);
      wait_vm<0>(); BAR();
    }
  }

  // iter 31 + drain
  QKT_M(31, stB);
  SMPV_M(30, stA);
  SMPV_M(31, stB);

#pragma unroll
  for (int qs = 0; qs < 2; ++qs) {
    float rs = (l_part[qs][0] + l_part[qs][1]) + (l_part[qs][2] + l_part[qs][3]);
    rs += __shfl_xor(rs, 16, 64);
    rs += __shfl_xor(rs, 32, 64);
#pragma unroll
    for (int r = 0; r < 4; ++r) {
      const float lq = __shfl(rs, kg * 4 + r, 64);
      const float inv = 1.0f / lq;
      const long row = rowbase + q0 + wave * 32 + qs * 16 + kg * 4 + r;
#pragma unroll
      for (int dt = 0; dt < 4; ++dt)
        attout[row * EDIM + h * HDIM + dt * 16 + lr] = f2bf(o_acc[qs][dt][r] * inv);
    }
  }
#undef ASTAGE
#undef QKT_M
#undef SMPV_M
#undef BAR
}

extern "C" void kernel_launch(void* const* d_in, const int* in_sizes, int n_in,
                              void* d_out, int out_size, void* d_ws, size_t ws_size,
                              hipStream_t stream) {
  const float* x      = (const float*)d_in[0];
  const float* w_qkv  = (const float*)d_in[1];
  const float* b_qkv  = (const float*)d_in[2];
  const float* w_proj = (const float*)d_in[3];
  const float* b_proj = (const float*)d_in[4];

  unsigned short* xb   = (unsigned short*)d_ws;              // 8.39M elems
  unsigned short* wqb  = xb   + (size_t)MROWS * EDIM;        // 3.15M
  unsigned short* wpb  = wqb  + (size_t)NQKV * EDIM;         // 1.05M
  unsigned short* qkb  = wpb  + (size_t)EDIM * EDIM;         // 16.8M ([8192][2048])
  unsigned short* attb = qkb  + (size_t)MROWS * QKB;         // 8.39M
  unsigned short* vTb  = attb + (size_t)MROWS * EDIM;        // 8.39M ([1024][8192])

  const int sh22 = 131072;  // (2+2) x 32KB
  const int sh12 = 98304;   // (1+2) x 32KB
  const int sh21 = 98304;   // (2+1) x 32KB
  hipFuncSetAttribute((const void*)gemm8p<0, 2, 2>,
                      hipFuncAttributeMaxDynamicSharedMemorySize, sh22);
  hipFuncSetAttribute((const void*)gemm8p<2, 1, 2>,
                      hipFuncAttributeMaxDynamicSharedMemorySize, sh12);
  hipFuncSetAttribute((const void*)gemm8p<1, 2, 1>,
                      hipFuncAttributeMaxDynamicSharedMemorySize, sh21);

  cvt_all<<<12288, 256, 0, stream>>>(x, w_qkv, w_proj, xb);

  // QK projection: [8192][2048] (Q pre-scaled into log2 domain). 256 wgs.
  gemm8p<0, 2, 2><<<(MROWS / 256) * (QKB / 256), 512, sh22, stream>>>(
      xb, wqb, b_qkv, qkb, MROWS, QKB, EDIM);

  // V^T directly (swapped operands -> scattered bf16 store). 128x256 tile.
  gemm8p<2, 1, 2><<<(EDIM / 128) * (MROWS / 256), 512, sh12, stream>>>(
      wqb + (size_t)2048 * EDIM, xb, b_qkv + 2048, vTb, EDIM, MROWS, EDIM);

  attn_fwd<<<512, 512, 0, stream>>>(qkb, vTb, attb);

  // proj: 256x128 tile.
  gemm8p<1, 2, 1><<<(MROWS / 256) * (EDIM / 128), 512, sh21, stream>>>(
      attb, wpb, b_proj, d_out, MROWS, EDIM, EDIM);
}

// Round 17
// 353.878 us; speedup vs baseline: 2.2721x; 1.5824x over previous
//
#include <hip/hip_runtime.h>

#define EDIM 1024
#define NHEADS 16
#define HDIM 64
#define SEQ 2048
#define BATCH 4
#define MROWS (BATCH * SEQ)   // 8192
#define NQKV (3 * EDIM)       // 3072
#define QKB 2048              // QK buffer row stride (Q cols 0..1023, K 1024..2047)

typedef __attribute__((ext_vector_type(4))) float f32x4;
typedef __attribute__((ext_vector_type(8))) short s16x8;
typedef __attribute__((ext_vector_type(4))) short s16x4;
typedef __attribute__((ext_vector_type(4))) unsigned int u32x4;

#define AS1 __attribute__((address_space(1)))
#define AS3 __attribute__((address_space(3)))
#define GLOAD_LDS16(g, l) __builtin_amdgcn_global_load_lds( \
    (AS1 void*)(void*)(g), (AS3 void*)(void*)(l), 16, 0, 0)

static __device__ __forceinline__ unsigned short f2bf(float f) {
  unsigned int u = __builtin_bit_cast(unsigned int, f);
  u += 0x7fffu + ((u >> 16) & 1u);   // RNE
  return (unsigned short)(u >> 16);
}

static __device__ __forceinline__ float fexp2(float x) {
  float r;
  asm("v_exp_f32 %0, %1" : "=v"(r) : "v"(x));
  return r;
}

static __device__ __forceinline__ unsigned int cvtpk(float a, float b) {
  unsigned int r;
  asm("v_cvt_pk_bf16_f32 %0, %1, %2" : "=v"(r) : "v"(a), "v"(b));
  return r;
}

static __device__ __forceinline__ f32x4 mfma_bf16(s16x8 a, s16x8 b, f32x4 c) {
  return __builtin_amdgcn_mfma_f32_16x16x32_bf16(a, b, c, 0, 0, 0);
}

// counted waitcnt with compile-time literal
template <int N>
static __device__ __forceinline__ void wait_vm() {
  if constexpr (N >= 8)      asm volatile("s_waitcnt lgkmcnt(0) vmcnt(8)" ::: "memory");
  else if constexpr (N == 6) asm volatile("s_waitcnt lgkmcnt(0) vmcnt(6)" ::: "memory");
  else if constexpr (N == 4) asm volatile("s_waitcnt lgkmcnt(0) vmcnt(4)" ::: "memory");
  else if constexpr (N == 3) asm volatile("s_waitcnt lgkmcnt(0) vmcnt(3)" ::: "memory");
  else if constexpr (N == 2) asm volatile("s_waitcnt lgkmcnt(0) vmcnt(2)" ::: "memory");
  else                       asm volatile("s_waitcnt lgkmcnt(0) vmcnt(0)" ::: "memory");
}

// one kernel converts x, w_qkv, w_proj (outputs contiguous in workspace)
__global__ void __launch_bounds__(256) cvt_all(const float* __restrict__ x,
                                               const float* __restrict__ wq,
                                               const float* __restrict__ wp,
                                               unsigned short* __restrict__ out) {
  const int i = blockIdx.x * 256 + threadIdx.x;   // float4 index
  const float* src;
  int j;
  if (i < 2097152) { src = x;  j = i; }
  else if (i < 2883584) { src = wq; j = i - 2097152; }
  else { src = wp; j = i - 2883584; }
  const float4 v = ((const float4*)src)[j];
  ushort4 o;
  o.x = f2bf(v.x); o.y = f2bf(v.y); o.z = f2bf(v.z); o.w = f2bf(v.w);
  ((ushort4*)out)[i] = o;
}

// ---------------------------------------------------------------------------
// 8-phase deep-pipelined GEMM (round-14, verified).
// ---------------------------------------------------------------------------
template <int MODE, int BMP, int BNP>
__global__ void __launch_bounds__(512, 2) gemm8p(const unsigned short* __restrict__ Ap,
                                                 const unsigned short* __restrict__ Bp,
                                                 const float* __restrict__ bias,
                                                 void* __restrict__ Cout,
                                                 int M, int N, int K) {
  extern __shared__ unsigned short lds[];
  constexpr int AHALF = BMP * 4096;   // u16: (BMP*64) rows x 64 cols
  constexpr int BHALF = BNP * 4096;
  constexpr int BBASE = 4 * AHALF;    // A region = 2 buf x 2 half

  const int tid = threadIdx.x;
  const int lane = tid & 63;
  const int wave = tid >> 6;        // 0..7
  const int wr = wave >> 2;         // 0..1  (M half)
  const int wc = wave & 3;          // 0..3  (N quarter)
  const int lr = lane & 15, kg = lane >> 4;

  const int nwg = gridDim.x;        // divisible by 8
  const int q8 = nwg >> 3;
  const int wgid = (blockIdx.x & 7) * q8 + (blockIdx.x >> 3);  // XCD-bijective
  const int NBM = M >> (BMP == 2 ? 8 : 7);
  const long m0 = (long)(wgid % NBM) * (BMP * 128);
  const long n0 = (long)(wgid / NBM) * (BNP * 128);

#define SA(buf, half, kt) do {                                                  \
    _Pragma("unroll")                                                           \
    for (int i_ = 0; i_ < BMP; ++i_) {                                          \
      const int rh_ = i_ * 64 + wave * 8 + (lane >> 3);                         \
      const int ce_ = ((lane & 7) ^ (lane >> 3)) * 8;                           \
      GLOAD_LDS16(Ap + (m0 + (half) * (BMP * 64) + rh_) * K + (kt) * 64 + ce_,  \
                  &lds[(buf) * 2 * AHALF + (half) * AHALF + i_ * 4096 + wave * 512]); \
    } } while (0)
#define SB(buf, half, kt) do {                                                  \
    _Pragma("unroll")                                                           \
    for (int i_ = 0; i_ < BNP; ++i_) {                                          \
      const int rh_ = i_ * 64 + wave * 8 + (lane >> 3);                         \
      const int ce_ = ((lane & 7) ^ (lane >> 3)) * 8;                           \
      GLOAD_LDS16(Bp + (n0 + (half) * (BNP * 64) + rh_) * K + (kt) * 64 + ce_,  \
                  &lds[BBASE + (buf) * 2 * BHALF + (half) * BHALF + i_ * 4096 + wave * 512]); \
    } } while (0)

#define PH_ENTER() do { __builtin_amdgcn_s_barrier();                           \
    asm volatile("s_waitcnt lgkmcnt(0)" ::: "memory");                          \
    __builtin_amdgcn_sched_barrier(0); } while (0)
#define PH_EXIT() __builtin_amdgcn_s_barrier()
#define PH_EXIT_VM() do { wait_vm<2 * BNP>();                                   \
    __builtin_amdgcn_sched_barrier(0);                                          \
    __builtin_amdgcn_s_barrier(); } while (0)
#define PH_EXIT_VM0() do { wait_vm<0>();                                        \
    __builtin_amdgcn_sched_barrier(0);                                          \
    __builtin_amdgcn_s_barrier(); } while (0)

  f32x4 acc[BMP * 4][BNP * 2] = {};
  s16x8 af[2 * BMP][2], bf0[BNP][2], bf1[BNP][2];

  auto LA = [&](int buf, int qm) {
#pragma unroll
    for (int m = 0; m < 2 * BMP; ++m) {
      const int rh = qm * (BMP * 32) + m * 16 + lr;
      const int ro = (buf * 2 + wr) * AHALF + rh * 64;
#pragma unroll
      for (int ks = 0; ks < 2; ++ks)
        af[m][ks] = *(const s16x8*)
            &lds[ro + (((ks * 64 + kg * 16) ^ ((rh & 7) << 4)) >> 1)];
    }
  };
  auto LB = [&](int buf, int qn, s16x8 (&bf)[BNP][2]) {
#pragma unroll
    for (int n = 0; n < BNP; ++n) {
      const int rh = (wc & 1) * (BNP * 32) + qn * (BNP * 16) + n * 16 + lr;
      const int ro = BBASE + (buf * 2 + (wc >> 1)) * BHALF + rh * 64;
#pragma unroll
      for (int ks = 0; ks < 2; ++ks)
        bf[n][ks] = *(const s16x8*)
            &lds[ro + (((ks * 64 + kg * 16) ^ ((rh & 7) << 4)) >> 1)];
    }
  };
  auto MM = [&](int qm, int qn, s16x8 (&bf)[BNP][2]) {
    __builtin_amdgcn_s_setprio(1);
#pragma unroll
    for (int m = 0; m < 2 * BMP; ++m)
#pragma unroll
      for (int n = 0; n < BNP; ++n)
#pragma unroll
        for (int ks = 0; ks < 2; ++ks)
          acc[qm * 2 * BMP + m][qn * BNP + n] =
              mfma_bf16(af[m][ks], bf[n][ks], acc[qm * 2 * BMP + m][qn * BNP + n]);
    __builtin_amdgcn_s_setprio(0);
  };

  const int nk = K >> 6;      // 64-wide K tiles (16)
  const int nit = nk >> 1;    // 8 iterations, 2 K-tiles each

  SB(0, 0, 0); SB(0, 1, 0);
  SA(0, 0, 0); SA(0, 1, 0);
  SB(1, 0, 1); SB(1, 1, 1);
  wait_vm<2 * BNP>();
  __builtin_amdgcn_sched_barrier(0);
  __builtin_amdgcn_s_barrier();
  __builtin_amdgcn_sched_barrier(0);

  for (int it = 0; it < nit; ++it) {
    const int ta = 2 * it, tb = 2 * it + 1;
    LA(0, 0); LB(0, 0, bf0);
    SA(1, 0, tb);
    PH_ENTER(); MM(0, 0, bf0); PH_EXIT();
    LB(0, 1, bf1);
    SA(1, 1, tb);
    PH_ENTER(); MM(0, 1, bf1); PH_EXIT();
    LA(0, 1);
    if (ta + 2 < nk) SB(0, 0, ta + 2);
    PH_ENTER(); MM(1, 0, bf0); PH_EXIT();
    if (ta + 2 < nk) SB(0, 1, ta + 2);
    PH_ENTER(); MM(1, 1, bf1);
    if (it + 1 < nit) { PH_EXIT_VM(); } else { PH_EXIT_VM0(); }
    LA(1, 0); LB(1, 0, bf0);
    if (ta + 2 < nk) SA(0, 0, ta + 2);
    PH_ENTER(); MM(0, 0, bf0); PH_EXIT();
    LB(1, 1, bf1);
    if (ta + 2 < nk) SA(0, 1, ta + 2);
    PH_ENTER(); MM(0, 1, bf1); PH_EXIT();
    LA(1, 1);
    if (tb + 2 < nk) SB(1, 0, tb + 2);
    PH_ENTER(); MM(1, 0, bf0); PH_EXIT();
    if (tb + 2 < nk) SB(1, 1, tb + 2);
    PH_ENTER(); MM(1, 1, bf1); PH_EXIT_VM();
  }

#pragma unroll
  for (int nt = 0; nt < BNP * 2; ++nt) {
    const long col = n0 + wc * (BNP * 32) + nt * 16 + lr;
    const float bv = (MODE == 2) ? 0.f : bias[col];
#pragma unroll
    for (int mt = 0; mt < BMP * 4; ++mt) {
#pragma unroll
      for (int r = 0; r < 4; ++r) {
        const long row = m0 + wr * (BMP * 64) + mt * 16 + kg * 4 + r;
        if (MODE == 0) {
          float v = acc[mt][nt][r] + bv;
          if (col < EDIM) v *= 0.18033688011112042f;  // 0.125 * log2(e)
          ((unsigned short*)Cout)[row * QKB + col] = f2bf(v);
        } else if (MODE == 1) {
          ((float*)Cout)[row * N + col] = acc[mt][nt][r] + bv;
        } else {
          const float v = acc[mt][nt][r] + bias[row];
          ((unsigned short*)Cout)[((col >> 11) * 1024 + row) * (long)2048 +
                                  (col & 2047)] = f2bf(v);
        }
      }
    }
  }
#undef SA
#undef SB
#undef PH_ENTER
#undef PH_EXIT
#undef PH_EXIT_VM
#undef PH_EXIT_VM0
}

// ---------------------------------------------------------------------------
// Flash attention — pk-carry pipeline. Iter t: stage(t+2); QKT(t)->st;
// PV(t-1, pk_prev) [independent MFMAs hide QK->exp latency]; exp(t)->pk_cur.
// Carried state = packed bf16 P (16 regs), not raw scores (32) — r15/r16
// spilled because carried st exceeded the 128-reg (512,4) budget.
// Sync shell = r16's (refcheck-proven): lead 2, wait_vm<2> steady.
// ---------------------------------------------------------------------------
__global__ void __launch_bounds__(512, 4) attn_fwd(const unsigned short* __restrict__ qk,
                                                   const unsigned short* __restrict__ vT,
                                                   unsigned short* __restrict__ attout) {
  const int L = blockIdx.x;
  const int bh = (L & 7) * 8 + (L >> 6);
  const int qt = (L >> 3) & 7;
  const int b = bh >> 4, h = bh & 15;
  const int q0 = qt * 256;
  const int tid = threadIdx.x, lane = tid & 63, wave = tid >> 6;  // wave 0..7
  const int lr = lane & 15, kg = lane >> 4;

  __shared__ unsigned short Ks[4][4096];   // [slot][k 64][d 64] swizzled
  __shared__ unsigned short Vs[4][4096];   // [slot][d 64][kv 64] swizzled

  const long rowbase = (long)b * SEQ;

#define ASTAGE(slot, kv0) do {                                                  \
    const int row_ = wave * 8 + (lane >> 3);                                    \
    const int col_ = ((lane & 7) ^ (lane >> 3)) << 3;                           \
    GLOAD_LDS16(qk + (rowbase + (kv0) + row_) * QKB + EDIM + h * HDIM + col_,   \
                &Ks[slot][wave * 512]);                                         \
    GLOAD_LDS16(vT + ((long)bh * HDIM + row_) * SEQ + (kv0) + col_,             \
                &Vs[slot][wave * 512]);                                         \
  } while (0)

  // QK^T of tile T into st (iteration-local)
#define QKT_M(T) do {                                                           \
    const unsigned short* Kb_ = Ks[(T) & 3];                                    \
    __builtin_amdgcn_s_setprio(1);                                              \
    _Pragma("unroll")                                                           \
    for (int ct = 0; ct < 4; ++ct) {                                            \
      const int rb_ = (ct * 16 + lr) * 128;                                     \
      const int sw_ = (lr & 7) << 4;                                            \
      const s16x8 k0_ = *(const s16x8*)&Kb_[(rb_ + ((kg * 16) ^ sw_)) >> 1];    \
      const s16x8 k1_ = *(const s16x8*)&Kb_[(rb_ + ((64 + kg * 16) ^ sw_)) >> 1];\
      _Pragma("unroll")                                                         \
      for (int qs = 0; qs < 2; ++qs) {                                          \
        f32x4 a_ = {};                                                          \
        a_ = mfma_bf16(k0_, qf[qs][0], a_);                                     \
        a_ = mfma_bf16(k1_, qf[qs][1], a_);                                     \
        st[qs][ct] = a_;                                                        \
      }                                                                         \
    }                                                                           \
    __builtin_amdgcn_s_setprio(0);                                              \
  } while (0)

  // exp + rowsum + pack st -> PK (carried, 16 u32)
#define EXP_M(PK) do {                                                          \
    _Pragma("unroll")                                                           \
    for (int qs = 0; qs < 2; ++qs) {                                            \
      f32x4 rv_ = {0.f, 0.f, 0.f, 0.f};                                         \
      _Pragma("unroll")                                                         \
      for (int ct = 0; ct < 4; ++ct) {                                          \
        f32x4 p_;                                                               \
        _Pragma("unroll")                                                       \
        for (int r = 0; r < 4; ++r) p_[r] = fexp2(st[qs][ct][r]);               \
        rv_ += p_;                                                              \
        PK[qs][ct][0] = cvtpk(p_[0], p_[1]);                                    \
        PK[qs][ct][1] = cvtpk(p_[2], p_[3]);                                    \
      }                                                                         \
      l_part[qs] += rv_;                                                        \
    }                                                                           \
  } while (0)

  // PV of tile T from carried PK (independent of current st/QKT)
#define PV_M(T, PK) do {                                                        \
    const unsigned short* Vb_ = Vs[(T) & 3];                                    \
    _Pragma("unroll")                                                           \
    for (int kc = 0; kc < 2; ++kc) {                                            \
      s16x8 pa_[2];                                                             \
      _Pragma("unroll")                                                         \
      for (int qs = 0; qs < 2; ++qs) {                                          \
        u32x4 wv_ = {PK[qs][2 * kc][0], PK[qs][2 * kc][1],                      \
                     PK[qs][2 * kc + 1][0], PK[qs][2 * kc + 1][1]};             \
        pa_[qs] = __builtin_bit_cast(s16x8, wv_);                               \
      }                                                                         \
      __builtin_amdgcn_s_setprio(1);                                            \
      _Pragma("unroll")                                                         \
      for (int dt = 0; dt < 4; ++dt) {                                          \
        const int rb_ = (dt * 16 + lr) * 128;                                   \
        const int c0_ = (64 * kc + 8 * kg) ^ ((lr & 7) << 4);                   \
        const s16x4 v0_ = *(const s16x4*)&Vb_[(rb_ + c0_) >> 1];                \
        const s16x4 v1_ = *(const s16x4*)&Vb_[(rb_ + (c0_ ^ 32)) >> 1];         \
        const s16x8 vf_ = __builtin_shufflevector(v0_, v1_, 0, 1, 2, 3, 4, 5, 6, 7); \
        _Pragma("unroll")                                                       \
        for (int qs = 0; qs < 2; ++qs)                                          \
          o_acc[qs][dt] = mfma_bf16(pa_[qs], vf_, o_acc[qs][dt]);               \
      }                                                                         \
      __builtin_amdgcn_s_setprio(0);                                            \
    }                                                                           \
  } while (0)

#define BAR() do { __builtin_amdgcn_s_barrier();                                \
    __builtin_amdgcn_sched_barrier(0); } while (0)

  s16x8 qf[2][2];
#pragma unroll
  for (int qs = 0; qs < 2; ++qs) {
    const unsigned short* qp =
        qk + (rowbase + q0 + wave * 32 + qs * 16 + lr) * QKB + h * HDIM + kg * 8;
    qf[qs][0] = *(const s16x8*)qp;
    qf[qs][1] = *(const s16x8*)(qp + 32);
  }

  f32x4 l_part[2] = {{0.f, 0.f, 0.f, 0.f}, {0.f, 0.f, 0.f, 0.f}};
  f32x4 o_acc[2][4] = {};
  f32x4 st[2][4];                 // iteration-local scores
  unsigned int pkA[2][4][2], pkB[2][4][2];   // carried packed P (16 regs each)

  // prologue: tiles 0,1 staged; tile 0 landed
  ASTAGE(0, 0); ASTAGE(1, 64);
  wait_vm<2>();
  __builtin_amdgcn_sched_barrier(0);
  BAR();

  // iter 0: no previous tile to PV
  ASTAGE(2, 128);
  QKT_M(0);
  EXP_M(pkA);
  wait_vm<2>(); BAR();

  // pairs (1,2),(3,4),...,(29,30)
  for (int t = 1; t <= 29; t += 2) {
    ASTAGE((t + 2) & 3, (t + 2) * 64);
    QKT_M(t);
    PV_M(t - 1, pkA);
    EXP_M(pkB);
    wait_vm<2>(); BAR();

    if (t + 3 < 32) {
      ASTAGE((t + 3) & 3, (t + 3) * 64);
      QKT_M(t + 1);
      PV_M(t, pkB);
      EXP_M(pkA);
      wait_vm<2>(); BAR();
    } else {
      QKT_M(t + 1);
      PV_M(t, pkB);
      EXP_M(pkA);
      wait_vm<0>(); BAR();
    }
  }

  // iter 31 + drain
  QKT_M(31);
  PV_M(30, pkA);
  EXP_M(pkB);
  PV_M(31, pkB);

#pragma unroll
  for (int qs = 0; qs < 2; ++qs) {
    float rs = (l_part[qs][0] + l_part[qs][1]) + (l_part[qs][2] + l_part[qs][3]);
    rs += __shfl_xor(rs, 16, 64);
    rs += __shfl_xor(rs, 32, 64);
#pragma unroll
    for (int r = 0; r < 4; ++r) {
      const float lq = __shfl(rs, kg * 4 + r, 64);
      const float inv = 1.0f / lq;
      const long row = rowbase + q0 + wave * 32 + qs * 16 + kg * 4 + r;
#pragma unroll
      for (int dt = 0; dt < 4; ++dt)
        attout[row * EDIM + h * HDIM + dt * 16 + lr] = f2bf(o_acc[qs][dt][r] * inv);
    }
  }
#undef ASTAGE
#undef QKT_M
#undef EXP_M
#undef PV_M
#undef BAR
}

extern "C" void kernel_launch(void* const* d_in, const int* in_sizes, int n_in,
                              void* d_out, int out_size, void* d_ws, size_t ws_size,
                              hipStream_t stream) {
  const float* x      = (const float*)d_in[0];
  const float* w_qkv  = (const float*)d_in[1];
  const float* b_qkv  = (const float*)d_in[2];
  const float* w_proj = (const float*)d_in[3];
  const float* b_proj = (const float*)d_in[4];

  unsigned short* xb   = (unsigned short*)d_ws;              // 8.39M elems
  unsigned short* wqb  = xb   + (size_t)MROWS * EDIM;        // 3.15M
  unsigned short* wpb  = wqb  + (size_t)NQKV * EDIM;         // 1.05M
  unsigned short* qkb  = wpb  + (size_t)EDIM * EDIM;         // 16.8M ([8192][2048])
  unsigned short* attb = qkb  + (size_t)MROWS * QKB;         // 8.39M
  unsigned short* vTb  = attb + (size_t)MROWS * EDIM;        // 8.39M ([1024][8192])

  const int sh22 = 131072;  // (2+2) x 32KB
  const int sh12 = 98304;   // (1+2) x 32KB
  const int sh21 = 98304;   // (2+1) x 32KB
  hipFuncSetAttribute((const void*)gemm8p<0, 2, 2>,
                      hipFuncAttributeMaxDynamicSharedMemorySize, sh22);
  hipFuncSetAttribute((const void*)gemm8p<2, 1, 2>,
                      hipFuncAttributeMaxDynamicSharedMemorySize, sh12);
  hipFuncSetAttribute((const void*)gemm8p<1, 2, 1>,
                      hipFuncAttributeMaxDynamicSharedMemorySize, sh21);

  cvt_all<<<12288, 256, 0, stream>>>(x, w_qkv, w_proj, xb);

  // QK projection: [8192][2048] (Q pre-scaled into log2 domain). 256 wgs.
  gemm8p<0, 2, 2><<<(MROWS / 256) * (QKB / 256), 512, sh22, stream>>>(
      xb, wqb, b_qkv, qkb, MROWS, QKB, EDIM);

  // V^T directly (swapped operands -> scattered bf16 store). 128x256 tile.
  gemm8p<2, 1, 2><<<(EDIM / 128) * (MROWS / 256), 512, sh12, stream>>>(
      wqb + (size_t)2048 * EDIM, xb, b_qkv + 2048, vTb, EDIM, MROWS, EDIM);

  attn_fwd<<<512, 512, 0, stream>>>(qkb, vTb, attb);

  // proj: 256x128 tile.
  gemm8p<1, 2, 1><<<(MROWS / 256) * (EDIM / 128), 512, sh21, stream>>>(
      attb, wpb, b_proj, d_out, MROWS, EDIM, EDIM);
}

// Round 18
// 187.380 us; speedup vs baseline: 4.2910x; 1.8886x over previous
//
#include <hip/hip_runtime.h>

#define EDIM 1024
#define NHEADS 16
#define HDIM 64
#define SEQ 2048
#define BATCH 4
#define MROWS (BATCH * SEQ)   // 8192
#define NQKV (3 * EDIM)       // 3072
#define QKB 2048              // QK buffer row stride (Q cols 0..1023, K 1024..2047)

typedef __attribute__((ext_vector_type(4))) float f32x4;
typedef __attribute__((ext_vector_type(8))) short s16x8;
typedef __attribute__((ext_vector_type(4))) short s16x4;
typedef __attribute__((ext_vector_type(4))) unsigned int u32x4;

#define AS1 __attribute__((address_space(1)))
#define AS3 __attribute__((address_space(3)))
#define GLOAD_LDS16(g, l) __builtin_amdgcn_global_load_lds( \
    (AS1 void*)(void*)(g), (AS3 void*)(void*)(l), 16, 0, 0)

static __device__ __forceinline__ unsigned short f2bf(float f) {
  unsigned int u = __builtin_bit_cast(unsigned int, f);
  u += 0x7fffu + ((u >> 16) & 1u);   // RNE
  return (unsigned short)(u >> 16);
}

static __device__ __forceinline__ float fexp2(float x) {
  float r;
  asm("v_exp_f32 %0, %1" : "=v"(r) : "v"(x));
  return r;
}

static __device__ __forceinline__ unsigned int cvtpk(float a, float b) {
  unsigned int r;
  asm("v_cvt_pk_bf16_f32 %0, %1, %2" : "=v"(r) : "v"(a), "v"(b));
  return r;
}

static __device__ __forceinline__ f32x4 mfma_bf16(s16x8 a, s16x8 b, f32x4 c) {
  return __builtin_amdgcn_mfma_f32_16x16x32_bf16(a, b, c, 0, 0, 0);
}

// counted waitcnt with compile-time literal
template <int N>
static __device__ __forceinline__ void wait_vm() {
  if constexpr (N >= 8)      asm volatile("s_waitcnt lgkmcnt(0) vmcnt(8)" ::: "memory");
  else if constexpr (N == 6) asm volatile("s_waitcnt lgkmcnt(0) vmcnt(6)" ::: "memory");
  else if constexpr (N == 4) asm volatile("s_waitcnt lgkmcnt(0) vmcnt(4)" ::: "memory");
  else if constexpr (N == 3) asm volatile("s_waitcnt lgkmcnt(0) vmcnt(3)" ::: "memory");
  else if constexpr (N == 2) asm volatile("s_waitcnt lgkmcnt(0) vmcnt(2)" ::: "memory");
  else                       asm volatile("s_waitcnt lgkmcnt(0) vmcnt(0)" ::: "memory");
}

// one kernel converts x, w_qkv, w_proj (outputs contiguous in workspace)
__global__ void __launch_bounds__(256) cvt_all(const float* __restrict__ x,
                                               const float* __restrict__ wq,
                                               const float* __restrict__ wp,
                                               unsigned short* __restrict__ out) {
  const int i = blockIdx.x * 256 + threadIdx.x;   // float4 index
  const float* src;
  int j;
  if (i < 2097152) { src = x;  j = i; }
  else if (i < 2883584) { src = wq; j = i - 2097152; }
  else { src = wp; j = i - 2883584; }
  const float4 v = ((const float4*)src)[j];
  ushort4 o;
  o.x = f2bf(v.x); o.y = f2bf(v.y); o.z = f2bf(v.z); o.w = f2bf(v.w);
  ((ushort4*)out)[i] = o;
}

// ---------------------------------------------------------------------------
// 8-phase deep-pipelined GEMM (round-14, verified).
// ---------------------------------------------------------------------------
template <int MODE, int BMP, int BNP>
__global__ void __launch_bounds__(512, 2) gemm8p(const unsigned short* __restrict__ Ap,
                                                 const unsigned short* __restrict__ Bp,
                                                 const float* __restrict__ bias,
                                                 void* __restrict__ Cout,
                                                 int M, int N, int K) {
  extern __shared__ unsigned short lds[];
  constexpr int AHALF = BMP * 4096;   // u16: (BMP*64) rows x 64 cols
  constexpr int BHALF = BNP * 4096;
  constexpr int BBASE = 4 * AHALF;    // A region = 2 buf x 2 half

  const int tid = threadIdx.x;
  const int lane = tid & 63;
  const int wave = tid >> 6;        // 0..7
  const int wr = wave >> 2;         // 0..1  (M half)
  const int wc = wave & 3;          // 0..3  (N quarter)
  const int lr = lane & 15, kg = lane >> 4;

  const int nwg = gridDim.x;        // divisible by 8
  const int q8 = nwg >> 3;
  const int wgid = (blockIdx.x & 7) * q8 + (blockIdx.x >> 3);  // XCD-bijective
  const int NBM = M >> (BMP == 2 ? 8 : 7);
  const long m0 = (long)(wgid % NBM) * (BMP * 128);
  const long n0 = (long)(wgid / NBM) * (BNP * 128);

#define SA(buf, half, kt) do {                                                  \
    _Pragma("unroll")                                                           \
    for (int i_ = 0; i_ < BMP; ++i_) {                                          \
      const int rh_ = i_ * 64 + wave * 8 + (lane >> 3);                         \
      const int ce_ = ((lane & 7) ^ (lane >> 3)) * 8;                           \
      GLOAD_LDS16(Ap + (m0 + (half) * (BMP * 64) + rh_) * K + (kt) * 64 + ce_,  \
                  &lds[(buf) * 2 * AHALF + (half) * AHALF + i_ * 4096 + wave * 512]); \
    } } while (0)
#define SB(buf, half, kt) do {                                                  \
    _Pragma("unroll")                                                           \
    for (int i_ = 0; i_ < BNP; ++i_) {                                          \
      const int rh_ = i_ * 64 + wave * 8 + (lane >> 3);                         \
      const int ce_ = ((lane & 7) ^ (lane >> 3)) * 8;                           \
      GLOAD_LDS16(Bp + (n0 + (half) * (BNP * 64) + rh_) * K + (kt) * 64 + ce_,  \
                  &lds[BBASE + (buf) * 2 * BHALF + (half) * BHALF + i_ * 4096 + wave * 512]); \
    } } while (0)

#define PH_ENTER() do { __builtin_amdgcn_s_barrier();                           \
    asm volatile("s_waitcnt lgkmcnt(0)" ::: "memory");                          \
    __builtin_amdgcn_sched_barrier(0); } while (0)
#define PH_EXIT() __builtin_amdgcn_s_barrier()
#define PH_EXIT_VM() do { wait_vm<2 * BNP>();                                   \
    __builtin_amdgcn_sched_barrier(0);                                          \
    __builtin_amdgcn_s_barrier(); } while (0)
#define PH_EXIT_VM0() do { wait_vm<0>();                                        \
    __builtin_amdgcn_sched_barrier(0);                                          \
    __builtin_amdgcn_s_barrier(); } while (0)

  f32x4 acc[BMP * 4][BNP * 2] = {};
  s16x8 af[2 * BMP][2], bf0[BNP][2], bf1[BNP][2];

  auto LA = [&](int buf, int qm) {
#pragma unroll
    for (int m = 0; m < 2 * BMP; ++m) {
      const int rh = qm * (BMP * 32) + m * 16 + lr;
      const int ro = (buf * 2 + wr) * AHALF + rh * 64;
#pragma unroll
      for (int ks = 0; ks < 2; ++ks)
        af[m][ks] = *(const s16x8*)
            &lds[ro + (((ks * 64 + kg * 16) ^ ((rh & 7) << 4)) >> 1)];
    }
  };
  auto LB = [&](int buf, int qn, s16x8 (&bf)[BNP][2]) {
#pragma unroll
    for (int n = 0; n < BNP; ++n) {
      const int rh = (wc & 1) * (BNP * 32) + qn * (BNP * 16) + n * 16 + lr;
      const int ro = BBASE + (buf * 2 + (wc >> 1)) * BHALF + rh * 64;
#pragma unroll
      for (int ks = 0; ks < 2; ++ks)
        bf[n][ks] = *(const s16x8*)
            &lds[ro + (((ks * 64 + kg * 16) ^ ((rh & 7) << 4)) >> 1)];
    }
  };
  auto MM = [&](int qm, int qn, s16x8 (&bf)[BNP][2]) {
    __builtin_amdgcn_s_setprio(1);
#pragma unroll
    for (int m = 0; m < 2 * BMP; ++m)
#pragma unroll
      for (int n = 0; n < BNP; ++n)
#pragma unroll
        for (int ks = 0; ks < 2; ++ks)
          acc[qm * 2 * BMP + m][qn * BNP + n] =
              mfma_bf16(af[m][ks], bf[n][ks], acc[qm * 2 * BMP + m][qn * BNP + n]);
    __builtin_amdgcn_s_setprio(0);
  };

  const int nk = K >> 6;      // 64-wide K tiles (16)
  const int nit = nk >> 1;    // 8 iterations, 2 K-tiles each

  SB(0, 0, 0); SB(0, 1, 0);
  SA(0, 0, 0); SA(0, 1, 0);
  SB(1, 0, 1); SB(1, 1, 1);
  wait_vm<2 * BNP>();
  __builtin_amdgcn_sched_barrier(0);
  __builtin_amdgcn_s_barrier();
  __builtin_amdgcn_sched_barrier(0);

  for (int it = 0; it < nit; ++it) {
    const int ta = 2 * it, tb = 2 * it + 1;
    LA(0, 0); LB(0, 0, bf0);
    SA(1, 0, tb);
    PH_ENTER(); MM(0, 0, bf0); PH_EXIT();
    LB(0, 1, bf1);
    SA(1, 1, tb);
    PH_ENTER(); MM(0, 1, bf1); PH_EXIT();
    LA(0, 1);
    if (ta + 2 < nk) SB(0, 0, ta + 2);
    PH_ENTER(); MM(1, 0, bf0); PH_EXIT();
    if (ta + 2 < nk) SB(0, 1, ta + 2);
    PH_ENTER(); MM(1, 1, bf1);
    if (it + 1 < nit) { PH_EXIT_VM(); } else { PH_EXIT_VM0(); }
    LA(1, 0); LB(1, 0, bf0);
    if (ta + 2 < nk) SA(0, 0, ta + 2);
    PH_ENTER(); MM(0, 0, bf0); PH_EXIT();
    LB(1, 1, bf1);
    if (ta + 2 < nk) SA(0, 1, ta + 2);
    PH_ENTER(); MM(0, 1, bf1); PH_EXIT();
    LA(1, 1);
    if (tb + 2 < nk) SB(1, 0, tb + 2);
    PH_ENTER(); MM(1, 0, bf0); PH_EXIT();
    if (tb + 2 < nk) SB(1, 1, tb + 2);
    PH_ENTER(); MM(1, 1, bf1); PH_EXIT_VM();
  }

#pragma unroll
  for (int nt = 0; nt < BNP * 2; ++nt) {
    const long col = n0 + wc * (BNP * 32) + nt * 16 + lr;
    const float bv = (MODE == 2) ? 0.f : bias[col];
#pragma unroll
    for (int mt = 0; mt < BMP * 4; ++mt) {
#pragma unroll
      for (int r = 0; r < 4; ++r) {
        const long row = m0 + wr * (BMP * 64) + mt * 16 + kg * 4 + r;
        if (MODE == 0) {
          float v = acc[mt][nt][r] + bv;
          if (col < EDIM) v *= 0.18033688011112042f;  // 0.125 * log2(e)
          ((unsigned short*)Cout)[row * QKB + col] = f2bf(v);
        } else if (MODE == 1) {
          ((float*)Cout)[row * N + col] = acc[mt][nt][r] + bv;
        } else {
          const float v = acc[mt][nt][r] + bias[row];
          ((unsigned short*)Cout)[((col >> 11) * 1024 + row) * (long)2048 +
                                  (col & 2047)] = f2bf(v);
        }
      }
    }
  }
#undef SA
#undef SB
#undef PH_ENTER
#undef PH_EXIT
#undef PH_EXIT_VM
#undef PH_EXIT_VM0
}

// ---------------------------------------------------------------------------
// Flash attention — round-14 configuration (verified best: 89.4 µs attn).
// KVBLK=64, 32 q-rows/wave, 512 thr / 8 waves, 4-slot counted-vmcnt pipeline.
// Serial per-tile body (QKT->exp->PV): fits the 64 arch-VGPR half of the
// unified file at (512,4); cross-tile carries spill (r15-r17 falsified).
// ---------------------------------------------------------------------------
__global__ void __launch_bounds__(512, 4) attn_fwd(const unsigned short* __restrict__ qk,
                                                   const unsigned short* __restrict__ vT,
                                                   unsigned short* __restrict__ attout) {
  const int L = blockIdx.x;
  const int bh = (L & 7) * 8 + (L >> 6);
  const int qt = (L >> 3) & 7;
  const int b = bh >> 4, h = bh & 15;
  const int q0 = qt * 256;
  const int tid = threadIdx.x, lane = tid & 63, wave = tid >> 6;  // wave 0..7
  const int lr = lane & 15, kg = lane >> 4;

  __shared__ unsigned short Ks[4][4096];   // [slot][k 64][d 64] swizzled
  __shared__ unsigned short Vs[4][4096];   // [slot][d 64][kv 64] swizzled

  const long rowbase = (long)b * SEQ;

#define ASTAGE(slot, kv0) do {                                                  \
    const int row_ = wave * 8 + (lane >> 3);                                    \
    const int col_ = ((lane & 7) ^ (lane >> 3)) << 3;                           \
    GLOAD_LDS16(qk + (rowbase + (kv0) + row_) * QKB + EDIM + h * HDIM + col_,   \
                &Ks[slot][wave * 512]);                                         \
    GLOAD_LDS16(vT + ((long)bh * HDIM + row_) * SEQ + (kv0) + col_,             \
                &Vs[slot][wave * 512]);                                         \
  } while (0)

  s16x8 qf[2][2];
#pragma unroll
  for (int qs = 0; qs < 2; ++qs) {
    const unsigned short* qp =
        qk + (rowbase + q0 + wave * 32 + qs * 16 + lr) * QKB + h * HDIM + kg * 8;
    qf[qs][0] = *(const s16x8*)qp;
    qf[qs][1] = *(const s16x8*)(qp + 32);
  }

  f32x4 l_part[2] = {{0.f, 0.f, 0.f, 0.f}, {0.f, 0.f, 0.f, 0.f}};
  f32x4 o_acc[2][4] = {};

  ASTAGE(0, 0); ASTAGE(1, 64); ASTAGE(2, 128);   // 6 loads in flight
  wait_vm<4>();                                  // tile 0 landed
  __builtin_amdgcn_s_barrier();
  __builtin_amdgcn_sched_barrier(0);

  for (int t = 0; t < 32; ++t) {
    if (t + 3 < 32) ASTAGE((t + 3) & 3, (t + 3) * 64);   // deep prefetch

    const unsigned short* Kb = Ks[t & 3];
    const unsigned short* Vb = Vs[t & 3];

    // ---- QK^T (log2 domain): lane holds S[k=ct*16+kg*4+r][q=lr] per qs
    f32x4 st[2][4];
    __builtin_amdgcn_s_setprio(1);
#pragma unroll
    for (int ct = 0; ct < 4; ++ct) {
      const int rb = (ct * 16 + lr) * 128;
      const int sw = (lr & 7) << 4;
      const s16x8 k0 = *(const s16x8*)&Kb[(rb + ((kg * 16) ^ sw)) >> 1];
      const s16x8 k1 = *(const s16x8*)&Kb[(rb + ((64 + kg * 16) ^ sw)) >> 1];
#pragma unroll
      for (int qs = 0; qs < 2; ++qs) {
        f32x4 a = {};
        a = mfma_bf16(k0, qf[qs][0], a);
        a = mfma_bf16(k1, qf[qs][1], a);
        st[qs][ct] = a;
      }
    }
    __builtin_amdgcn_s_setprio(0);

    // ---- p = 2^s, lane-local rowsum, pack to bf16
    unsigned int pk[2][4][2];
#pragma unroll
    for (int qs = 0; qs < 2; ++qs) {
      f32x4 rv = {0.f, 0.f, 0.f, 0.f};
#pragma unroll
      for (int ct = 0; ct < 4; ++ct) {
        f32x4 p;
#pragma unroll
        for (int r = 0; r < 4; ++r) p[r] = fexp2(st[qs][ct][r]);
        rv += p;
        pk[qs][ct][0] = cvtpk(p[0], p[1]);
        pk[qs][ct][1] = cvtpk(p[2], p[3]);
      }
      l_part[qs] += rv;
    }

    // ---- PV, zero-shuffle: sigma(kc,kg,j)=32kc+16(j>>2)+4kg+(j&3) on P and V
#pragma unroll
    for (int kc = 0; kc < 2; ++kc) {
      s16x8 pa[2];
#pragma unroll
      for (int qs = 0; qs < 2; ++qs) {
        u32x4 wv = {pk[qs][2 * kc][0], pk[qs][2 * kc][1],
                    pk[qs][2 * kc + 1][0], pk[qs][2 * kc + 1][1]};
        pa[qs] = __builtin_bit_cast(s16x8, wv);
      }
      __builtin_amdgcn_s_setprio(1);
#pragma unroll
      for (int dt = 0; dt < 4; ++dt) {
        const int rb = (dt * 16 + lr) * 128;
        const int c0 = (64 * kc + 8 * kg) ^ ((lr & 7) << 4);
        const s16x4 v0 = *(const s16x4*)&Vb[(rb + c0) >> 1];
        const s16x4 v1 = *(const s16x4*)&Vb[(rb + (c0 ^ 32)) >> 1];
        const s16x8 vf = __builtin_shufflevector(v0, v1, 0, 1, 2, 3, 4, 5, 6, 7);
#pragma unroll
        for (int qs = 0; qs < 2; ++qs)
          o_acc[qs][dt] = mfma_bf16(pa[qs], vf, o_acc[qs][dt]);
      }
      __builtin_amdgcn_s_setprio(0);
    }

    if (t + 1 < 32) {   // tile t+1 landed chip-wide after this barrier
      if (t + 3 < 32)      wait_vm<4>();
      else if (t + 2 < 32) wait_vm<2>();
      else                 wait_vm<0>();
      __builtin_amdgcn_s_barrier();
      __builtin_amdgcn_sched_barrier(0);
    }
  }

#pragma unroll
  for (int qs = 0; qs < 2; ++qs) {
    float rs = (l_part[qs][0] + l_part[qs][1]) + (l_part[qs][2] + l_part[qs][3]);
    rs += __shfl_xor(rs, 16, 64);
    rs += __shfl_xor(rs, 32, 64);
#pragma unroll
    for (int r = 0; r < 4; ++r) {
      const float lq = __shfl(rs, kg * 4 + r, 64);
      const float inv = 1.0f / lq;
      const long row = rowbase + q0 + wave * 32 + qs * 16 + kg * 4 + r;
#pragma unroll
      for (int dt = 0; dt < 4; ++dt)
        attout[row * EDIM + h * HDIM + dt * 16 + lr] = f2bf(o_acc[qs][dt][r] * inv);
    }
  }
#undef ASTAGE
}

extern "C" void kernel_launch(void* const* d_in, const int* in_sizes, int n_in,
                              void* d_out, int out_size, void* d_ws, size_t ws_size,
                              hipStream_t stream) {
  const float* x      = (const float*)d_in[0];
  const float* w_qkv  = (const float*)d_in[1];
  const float* b_qkv  = (const float*)d_in[2];
  const float* w_proj = (const float*)d_in[3];
  const float* b_proj = (const float*)d_in[4];

  unsigned short* xb   = (unsigned short*)d_ws;              // 8.39M elems
  unsigned short* wqb  = xb   + (size_t)MROWS * EDIM;        // 3.15M
  unsigned short* wpb  = wqb  + (size_t)NQKV * EDIM;         // 1.05M
  unsigned short* qkb  = wpb  + (size_t)EDIM * EDIM;         // 16.8M ([8192][2048])
  unsigned short* attb = qkb  + (size_t)MROWS * QKB;         // 8.39M
  unsigned short* vTb  = attb + (size_t)MROWS * EDIM;        // 8.39M ([1024][8192])

  const int sh22 = 131072;  // (2+2) x 32KB
  const int sh12 = 98304;   // (1+2) x 32KB
  const int sh21 = 98304;   // (2+1) x 32KB
  hipFuncSetAttribute((const void*)gemm8p<0, 2, 2>,
                      hipFuncAttributeMaxDynamicSharedMemorySize, sh22);
  hipFuncSetAttribute((const void*)gemm8p<2, 1, 2>,
                      hipFuncAttributeMaxDynamicSharedMemorySize, sh12);
  hipFuncSetAttribute((const void*)gemm8p<1, 2, 1>,
                      hipFuncAttributeMaxDynamicSharedMemorySize, sh21);

  cvt_all<<<12288, 256, 0, stream>>>(x, w_qkv, w_proj, xb);

  // QK projection: [8192][2048] (Q pre-scaled into log2 domain). 256 wgs.
  gemm8p<0, 2, 2><<<(MROWS / 256) * (QKB / 256), 512, sh22, stream>>>(
      xb, wqb, b_qkv, qkb, MROWS, QKB, EDIM);

  // V^T directly (swapped operands -> scattered bf16 store). 128x256 tile.
  gemm8p<2, 1, 2><<<(EDIM / 128) * (MROWS / 256), 512, sh12, stream>>>(
      wqb + (size_t)2048 * EDIM, xb, b_qkv + 2048, vTb, EDIM, MROWS, EDIM);

  attn_fwd<<<512, 512, 0, stream>>>(qkb, vTb, attb);

  // proj: 256x128 tile.
  gemm8p<1, 2, 1><<<(MROWS / 256) * (EDIM / 128), 512, sh21, stream>>>(
      attb, wpb, b_proj, d_out, MROWS, EDIM, EDIM);
}

// Round 19
// 184.105 us; speedup vs baseline: 4.3673x; 1.0178x over previous
//
#include <hip/hip_runtime.h>

#define EDIM 1024
#define NHEADS 16
#define HDIM 64
#define SEQ 2048
#define BATCH 4
#define MROWS (BATCH * SEQ)   // 8192
#define NQKV (3 * EDIM)       // 3072
#define QKB 2048              // QK buffer row stride (Q cols 0..1023, K 1024..2047)

typedef __attribute__((ext_vector_type(4))) float f32x4;
typedef __attribute__((ext_vector_type(8))) short s16x8;
typedef __attribute__((ext_vector_type(4))) short s16x4;
typedef __attribute__((ext_vector_type(4))) unsigned int u32x4;

#define AS1 __attribute__((address_space(1)))
#define AS3 __attribute__((address_space(3)))
#define GLOAD_LDS16(g, l) __builtin_amdgcn_global_load_lds( \
    (AS1 void*)(void*)(g), (AS3 void*)(void*)(l), 16, 0, 0)

static __device__ __forceinline__ unsigned short f2bf(float f) {
  unsigned int u = __builtin_bit_cast(unsigned int, f);
  u += 0x7fffu + ((u >> 16) & 1u);   // RNE
  return (unsigned short)(u >> 16);
}

static __device__ __forceinline__ float fexp2(float x) {
  float r;
  asm("v_exp_f32 %0, %1" : "=v"(r) : "v"(x));
  return r;
}

static __device__ __forceinline__ unsigned int cvtpk(float a, float b) {
  unsigned int r;
  asm("v_cvt_pk_bf16_f32 %0, %1, %2" : "=v"(r) : "v"(a), "v"(b));
  return r;
}

static __device__ __forceinline__ f32x4 mfma_bf16(s16x8 a, s16x8 b, f32x4 c) {
  return __builtin_amdgcn_mfma_f32_16x16x32_bf16(a, b, c, 0, 0, 0);
}

// counted waitcnt with compile-time literal
template <int N>
static __device__ __forceinline__ void wait_vm() {
  if constexpr (N >= 8)      asm volatile("s_waitcnt lgkmcnt(0) vmcnt(8)" ::: "memory");
  else if constexpr (N == 6) asm volatile("s_waitcnt lgkmcnt(0) vmcnt(6)" ::: "memory");
  else if constexpr (N == 4) asm volatile("s_waitcnt lgkmcnt(0) vmcnt(4)" ::: "memory");
  else if constexpr (N == 3) asm volatile("s_waitcnt lgkmcnt(0) vmcnt(3)" ::: "memory");
  else if constexpr (N == 2) asm volatile("s_waitcnt lgkmcnt(0) vmcnt(2)" ::: "memory");
  else                       asm volatile("s_waitcnt lgkmcnt(0) vmcnt(0)" ::: "memory");
}

// one kernel converts x, w_qkv, w_proj (outputs contiguous in workspace)
__global__ void __launch_bounds__(256) cvt_all(const float* __restrict__ x,
                                               const float* __restrict__ wq,
                                               const float* __restrict__ wp,
                                               unsigned short* __restrict__ out) {
  const int i = blockIdx.x * 256 + threadIdx.x;   // float4 index
  const float* src;
  int j;
  if (i < 2097152) { src = x;  j = i; }
  else if (i < 2883584) { src = wq; j = i - 2097152; }
  else { src = wp; j = i - 2883584; }
  const float4 v = ((const float4*)src)[j];
  ushort4 o;
  o.x = f2bf(v.x); o.y = f2bf(v.y); o.z = f2bf(v.z); o.w = f2bf(v.w);
  ((ushort4*)out)[i] = o;
}

// ---------------------------------------------------------------------------
// 8-phase deep-pipelined GEMM (round-14, verified).
// ---------------------------------------------------------------------------
template <int MODE, int BMP, int BNP>
__global__ void __launch_bounds__(512, 2) gemm8p(const unsigned short* __restrict__ Ap,
                                                 const unsigned short* __restrict__ Bp,
                                                 const float* __restrict__ bias,
                                                 void* __restrict__ Cout,
                                                 int M, int N, int K) {
  extern __shared__ unsigned short lds[];
  constexpr int AHALF = BMP * 4096;   // u16: (BMP*64) rows x 64 cols
  constexpr int BHALF = BNP * 4096;
  constexpr int BBASE = 4 * AHALF;    // A region = 2 buf x 2 half

  const int tid = threadIdx.x;
  const int lane = tid & 63;
  const int wave = tid >> 6;        // 0..7
  const int wr = wave >> 2;         // 0..1  (M half)
  const int wc = wave & 3;          // 0..3  (N quarter)
  const int lr = lane & 15, kg = lane >> 4;

  const int nwg = gridDim.x;        // divisible by 8
  const int q8 = nwg >> 3;
  const int wgid = (blockIdx.x & 7) * q8 + (blockIdx.x >> 3);  // XCD-bijective
  const int NBM = M >> (BMP == 2 ? 8 : 7);
  const long m0 = (long)(wgid % NBM) * (BMP * 128);
  const long n0 = (long)(wgid / NBM) * (BNP * 128);

#define SA(buf, half, kt) do {                                                  \
    _Pragma("unroll")                                                           \
    for (int i_ = 0; i_ < BMP; ++i_) {                                          \
      const int rh_ = i_ * 64 + wave * 8 + (lane >> 3);                         \
      const int ce_ = ((lane & 7) ^ (lane >> 3)) * 8;                           \
      GLOAD_LDS16(Ap + (m0 + (half) * (BMP * 64) + rh_) * K + (kt) * 64 + ce_,  \
                  &lds[(buf) * 2 * AHALF + (half) * AHALF + i_ * 4096 + wave * 512]); \
    } } while (0)
#define SB(buf, half, kt) do {                                                  \
    _Pragma("unroll")                                                           \
    for (int i_ = 0; i_ < BNP; ++i_) {                                          \
      const int rh_ = i_ * 64 + wave * 8 + (lane >> 3);                         \
      const int ce_ = ((lane & 7) ^ (lane >> 3)) * 8;                           \
      GLOAD_LDS16(Bp + (n0 + (half) * (BNP * 64) + rh_) * K + (kt) * 64 + ce_,  \
                  &lds[BBASE + (buf) * 2 * BHALF + (half) * BHALF + i_ * 4096 + wave * 512]); \
    } } while (0)

#define PH_ENTER() do { __builtin_amdgcn_s_barrier();                           \
    asm volatile("s_waitcnt lgkmcnt(0)" ::: "memory");                          \
    __builtin_amdgcn_sched_barrier(0); } while (0)
#define PH_EXIT() __builtin_amdgcn_s_barrier()
#define PH_EXIT_VM() do { wait_vm<2 * BNP>();                                   \
    __builtin_amdgcn_sched_barrier(0);                                          \
    __builtin_amdgcn_s_barrier(); } while (0)
#define PH_EXIT_VM0() do { wait_vm<0>();                                        \
    __builtin_amdgcn_sched_barrier(0);                                          \
    __builtin_amdgcn_s_barrier(); } while (0)

  f32x4 acc[BMP * 4][BNP * 2] = {};
  s16x8 af[2 * BMP][2], bf0[BNP][2], bf1[BNP][2];

  auto LA = [&](int buf, int qm) {
#pragma unroll
    for (int m = 0; m < 2 * BMP; ++m) {
      const int rh = qm * (BMP * 32) + m * 16 + lr;
      const int ro = (buf * 2 + wr) * AHALF + rh * 64;
#pragma unroll
      for (int ks = 0; ks < 2; ++ks)
        af[m][ks] = *(const s16x8*)
            &lds[ro + (((ks * 64 + kg * 16) ^ ((rh & 7) << 4)) >> 1)];
    }
  };
  auto LB = [&](int buf, int qn, s16x8 (&bf)[BNP][2]) {
#pragma unroll
    for (int n = 0; n < BNP; ++n) {
      const int rh = (wc & 1) * (BNP * 32) + qn * (BNP * 16) + n * 16 + lr;
      const int ro = BBASE + (buf * 2 + (wc >> 1)) * BHALF + rh * 64;
#pragma unroll
      for (int ks = 0; ks < 2; ++ks)
        bf[n][ks] = *(const s16x8*)
            &lds[ro + (((ks * 64 + kg * 16) ^ ((rh & 7) << 4)) >> 1)];
    }
  };
  auto MM = [&](int qm, int qn, s16x8 (&bf)[BNP][2]) {
    __builtin_amdgcn_s_setprio(1);
#pragma unroll
    for (int m = 0; m < 2 * BMP; ++m)
#pragma unroll
      for (int n = 0; n < BNP; ++n)
#pragma unroll
        for (int ks = 0; ks < 2; ++ks)
          acc[qm * 2 * BMP + m][qn * BNP + n] =
              mfma_bf16(af[m][ks], bf[n][ks], acc[qm * 2 * BMP + m][qn * BNP + n]);
    __builtin_amdgcn_s_setprio(0);
  };

  const int nk = K >> 6;      // 64-wide K tiles (16)
  const int nit = nk >> 1;    // 8 iterations, 2 K-tiles each

  SB(0, 0, 0); SB(0, 1, 0);
  SA(0, 0, 0); SA(0, 1, 0);
  SB(1, 0, 1); SB(1, 1, 1);
  wait_vm<2 * BNP>();
  __builtin_amdgcn_sched_barrier(0);
  __builtin_amdgcn_s_barrier();
  __builtin_amdgcn_sched_barrier(0);

  for (int it = 0; it < nit; ++it) {
    const int ta = 2 * it, tb = 2 * it + 1;
    LA(0, 0); LB(0, 0, bf0);
    SA(1, 0, tb);
    PH_ENTER(); MM(0, 0, bf0); PH_EXIT();
    LB(0, 1, bf1);
    SA(1, 1, tb);
    PH_ENTER(); MM(0, 1, bf1); PH_EXIT();
    LA(0, 1);
    if (ta + 2 < nk) SB(0, 0, ta + 2);
    PH_ENTER(); MM(1, 0, bf0); PH_EXIT();
    if (ta + 2 < nk) SB(0, 1, ta + 2);
    PH_ENTER(); MM(1, 1, bf1);
    if (it + 1 < nit) { PH_EXIT_VM(); } else { PH_EXIT_VM0(); }
    LA(1, 0); LB(1, 0, bf0);
    if (ta + 2 < nk) SA(0, 0, ta + 2);
    PH_ENTER(); MM(0, 0, bf0); PH_EXIT();
    LB(1, 1, bf1);
    if (ta + 2 < nk) SA(0, 1, ta + 2);
    PH_ENTER(); MM(0, 1, bf1); PH_EXIT();
    LA(1, 1);
    if (tb + 2 < nk) SB(1, 0, tb + 2);
    PH_ENTER(); MM(1, 0, bf0); PH_EXIT();
    if (tb + 2 < nk) SB(1, 1, tb + 2);
    PH_ENTER(); MM(1, 1, bf1); PH_EXIT_VM();
  }

#pragma unroll
  for (int nt = 0; nt < BNP * 2; ++nt) {
    const long col = n0 + wc * (BNP * 32) + nt * 16 + lr;
    const float bv = (MODE == 2) ? 0.f : bias[col];
#pragma unroll
    for (int mt = 0; mt < BMP * 4; ++mt) {
#pragma unroll
      for (int r = 0; r < 4; ++r) {
        const long row = m0 + wr * (BMP * 64) + mt * 16 + kg * 4 + r;
        if (MODE == 0) {
          float v = acc[mt][nt][r] + bv;
          if (col < EDIM) v *= 0.18033688011112042f;  // 0.125 * log2(e)
          ((unsigned short*)Cout)[row * QKB + col] = f2bf(v);
        } else if (MODE == 1) {
          ((float*)Cout)[row * N + col] = acc[mt][nt][r] + bv;
        } else {
          const float v = acc[mt][nt][r] + bias[row];
          ((unsigned short*)Cout)[((col >> 11) * 1024 + row) * (long)2048 +
                                  (col & 2047)] = f2bf(v);
        }
      }
    }
  }
#undef SA
#undef SB
#undef PH_ENTER
#undef PH_EXIT
#undef PH_EXIT_VM
#undef PH_EXIT_VM0
}

// ---------------------------------------------------------------------------
// Flash attention — r14 shell, PAIR-UNROLLED: two tile bodies per iteration,
// one barrier per pair (16 vs 32). Stage pair p+1 at iteration start; drain
// late (wait covers ~2 tile bodies of latency). Serial per-tile body (shared
// st) — no extra carried registers (r15-17 showed carries spill at 64 VGPR).
// Slot walk: iter p reads slots {2p&3,(2p+1)&3}, stages the other two, which
// hold pair p-1's tiles last read before the previous barrier.
// ---------------------------------------------------------------------------
__global__ void __launch_bounds__(512, 4) attn_fwd(const unsigned short* __restrict__ qk,
                                                   const unsigned short* __restrict__ vT,
                                                   unsigned short* __restrict__ attout) {
  const int L = blockIdx.x;
  const int bh = (L & 7) * 8 + (L >> 6);
  const int qt = (L >> 3) & 7;
  const int b = bh >> 4, h = bh & 15;
  const int q0 = qt * 256;
  const int tid = threadIdx.x, lane = tid & 63, wave = tid >> 6;  // wave 0..7
  const int lr = lane & 15, kg = lane >> 4;

  __shared__ unsigned short Ks[4][4096];   // [slot][k 64][d 64] swizzled
  __shared__ unsigned short Vs[4][4096];   // [slot][d 64][kv 64] swizzled

  const long rowbase = (long)b * SEQ;

#define ASTAGE(slot, kv0) do {                                                  \
    const int row_ = wave * 8 + (lane >> 3);                                    \
    const int col_ = ((lane & 7) ^ (lane >> 3)) << 3;                           \
    GLOAD_LDS16(qk + (rowbase + (kv0) + row_) * QKB + EDIM + h * HDIM + col_,   \
                &Ks[slot][wave * 512]);                                         \
    GLOAD_LDS16(vT + ((long)bh * HDIM + row_) * SEQ + (kv0) + col_,             \
                &Vs[slot][wave * 512]);                                         \
  } while (0)

  // full per-tile body: QK^T (log2 domain) -> exp/rowsum/pack -> PV
#define TILE_BODY(T) do {                                                       \
    const unsigned short* Kb_ = Ks[(T) & 3];                                    \
    const unsigned short* Vb_ = Vs[(T) & 3];                                    \
    f32x4 st[2][4];                                                             \
    __builtin_amdgcn_s_setprio(1);                                              \
    _Pragma("unroll")                                                           \
    for (int ct = 0; ct < 4; ++ct) {                                            \
      const int rb_ = (ct * 16 + lr) * 128;                                     \
      const int sw_ = (lr & 7) << 4;                                            \
      const s16x8 k0_ = *(const s16x8*)&Kb_[(rb_ + ((kg * 16) ^ sw_)) >> 1];    \
      const s16x8 k1_ = *(const s16x8*)&Kb_[(rb_ + ((64 + kg * 16) ^ sw_)) >> 1];\
      _Pragma("unroll")                                                         \
      for (int qs = 0; qs < 2; ++qs) {                                          \
        f32x4 a_ = {};                                                          \
        a_ = mfma_bf16(k0_, qf[qs][0], a_);                                     \
        a_ = mfma_bf16(k1_, qf[qs][1], a_);                                     \
        st[qs][ct] = a_;                                                        \
      }                                                                         \
    }                                                                           \
    __builtin_amdgcn_s_setprio(0);                                              \
    unsigned int pk[2][4][2];                                                   \
    _Pragma("unroll")                                                           \
    for (int qs = 0; qs < 2; ++qs) {                                            \
      f32x4 rv_ = {0.f, 0.f, 0.f, 0.f};                                         \
      _Pragma("unroll")                                                         \
      for (int ct = 0; ct < 4; ++ct) {                                          \
        f32x4 p_;                                                               \
        _Pragma("unroll")                                                       \
        for (int r = 0; r < 4; ++r) p_[r] = fexp2(st[qs][ct][r]);               \
        rv_ += p_;                                                              \
        pk[qs][ct][0] = cvtpk(p_[0], p_[1]);                                    \
        pk[qs][ct][1] = cvtpk(p_[2], p_[3]);                                    \
      }                                                                         \
      l_part[qs] += rv_;                                                        \
    }                                                                           \
    _Pragma("unroll")                                                           \
    for (int kc = 0; kc < 2; ++kc) {                                            \
      s16x8 pa_[2];                                                             \
      _Pragma("unroll")                                                         \
      for (int qs = 0; qs < 2; ++qs) {                                          \
        u32x4 wv_ = {pk[qs][2 * kc][0], pk[qs][2 * kc][1],                      \
                     pk[qs][2 * kc + 1][0], pk[qs][2 * kc + 1][1]};             \
        pa_[qs] = __builtin_bit_cast(s16x8, wv_);                               \
      }                                                                         \
      __builtin_amdgcn_s_setprio(1);                                            \
      _Pragma("unroll")                                                         \
      for (int dt = 0; dt < 4; ++dt) {                                          \
        const int rb_ = (dt * 16 + lr) * 128;                                   \
        const int c0_ = (64 * kc + 8 * kg) ^ ((lr & 7) << 4);                   \
        const s16x4 v0_ = *(const s16x4*)&Vb_[(rb_ + c0_) >> 1];                \
        const s16x4 v1_ = *(const s16x4*)&Vb_[(rb_ + (c0_ ^ 32)) >> 1];         \
        const s16x8 vf_ = __builtin_shufflevector(v0_, v1_, 0, 1, 2, 3, 4, 5, 6, 7); \
        _Pragma("unroll")                                                       \
        for (int qs = 0; qs < 2; ++qs)                                          \
          o_acc[qs][dt] = mfma_bf16(pa_[qs], vf_, o_acc[qs][dt]);               \
      }                                                                         \
      __builtin_amdgcn_s_setprio(0);                                            \
    }                                                                           \
  } while (0)

  s16x8 qf[2][2];
#pragma unroll
  for (int qs = 0; qs < 2; ++qs) {
    const unsigned short* qp =
        qk + (rowbase + q0 + wave * 32 + qs * 16 + lr) * QKB + h * HDIM + kg * 8;
    qf[qs][0] = *(const s16x8*)qp;
    qf[qs][1] = *(const s16x8*)(qp + 32);
  }

  f32x4 l_part[2] = {{0.f, 0.f, 0.f, 0.f}, {0.f, 0.f, 0.f, 0.f}};
  f32x4 o_acc[2][4] = {};

  // prologue: pair 0 staged and landed
  ASTAGE(0, 0); ASTAGE(1, 64);
  wait_vm<0>();
  __builtin_amdgcn_s_barrier();
  __builtin_amdgcn_sched_barrier(0);

  for (int p = 0; p < 16; ++p) {
    const int t0 = 2 * p;
    if (p + 1 < 16) {   // stage next pair early — latency hidden by 2 bodies
      ASTAGE((t0 + 2) & 3, (t0 + 2) * 64);
      ASTAGE((t0 + 3) & 3, (t0 + 3) * 64);
    }
    TILE_BODY(t0);
    TILE_BODY(t0 + 1);
    wait_vm<0>();       // next pair landed (issued ~2 bodies ago)
    __builtin_amdgcn_s_barrier();
    __builtin_amdgcn_sched_barrier(0);
  }

#pragma unroll
  for (int qs = 0; qs < 2; ++qs) {
    float rs = (l_part[qs][0] + l_part[qs][1]) + (l_part[qs][2] + l_part[qs][3]);
    rs += __shfl_xor(rs, 16, 64);
    rs += __shfl_xor(rs, 32, 64);
#pragma unroll
    for (int r = 0; r < 4; ++r) {
      const float lq = __shfl(rs, kg * 4 + r, 64);
      const float inv = 1.0f / lq;
      const long row = rowbase + q0 + wave * 32 + qs * 16 + kg * 4 + r;
#pragma unroll
      for (int dt = 0; dt < 4; ++dt)
        attout[row * EDIM + h * HDIM + dt * 16 + lr] = f2bf(o_acc[qs][dt][r] * inv);
    }
  }
#undef ASTAGE
#undef TILE_BODY
}

extern "C" void kernel_launch(void* const* d_in, const int* in_sizes, int n_in,
                              void* d_out, int out_size, void* d_ws, size_t ws_size,
                              hipStream_t stream) {
  const float* x      = (const float*)d_in[0];
  const float* w_qkv  = (const float*)d_in[1];
  const float* b_qkv  = (const float*)d_in[2];
  const float* w_proj = (const float*)d_in[3];
  const float* b_proj = (const float*)d_in[4];

  unsigned short* xb   = (unsigned short*)d_ws;              // 8.39M elems
  unsigned short* wqb  = xb   + (size_t)MROWS * EDIM;        // 3.15M
  unsigned short* wpb  = wqb  + (size_t)NQKV * EDIM;         // 1.05M
  unsigned short* qkb  = wpb  + (size_t)EDIM * EDIM;         // 16.8M ([8192][2048])
  unsigned short* attb = qkb  + (size_t)MROWS * QKB;         // 8.39M
  unsigned short* vTb  = attb + (size_t)MROWS * EDIM;        // 8.39M ([1024][8192])

  const int sh22 = 131072;  // (2+2) x 32KB
  const int sh12 = 98304;   // (1+2) x 32KB
  const int sh21 = 98304;   // (2+1) x 32KB
  hipFuncSetAttribute((const void*)gemm8p<0, 2, 2>,
                      hipFuncAttributeMaxDynamicSharedMemorySize, sh22);
  hipFuncSetAttribute((const void*)gemm8p<2, 1, 2>,
                      hipFuncAttributeMaxDynamicSharedMemorySize, sh12);
  hipFuncSetAttribute((const void*)gemm8p<1, 2, 1>,
                      hipFuncAttributeMaxDynamicSharedMemorySize, sh21);

  cvt_all<<<12288, 256, 0, stream>>>(x, w_qkv, w_proj, xb);

  // QK projection: [8192][2048] (Q pre-scaled into log2 domain). 256 wgs.
  gemm8p<0, 2, 2><<<(MROWS / 256) * (QKB / 256), 512, sh22, stream>>>(
      xb, wqb, b_qkv, qkb, MROWS, QKB, EDIM);

  // V^T directly (swapped operands -> scattered bf16 store). 128x256 tile.
  gemm8p<2, 1, 2><<<(EDIM / 128) * (MROWS / 256), 512, sh12, stream>>>(
      wqb + (size_t)2048 * EDIM, xb, b_qkv + 2048, vTb, EDIM, MROWS, EDIM);

  attn_fwd<<<512, 512, 0, stream>>>(qkb, vTb, attb);

  // proj: 256x128 tile.
  gemm8p<1, 2, 1><<<(MROWS / 256) * (EDIM / 128), 512, sh21, stream>>>(
      attb, wpb, b_proj, d_out, MROWS, EDIM, EDIM);
}

// Round 20
// 180.447 us; speedup vs baseline: 4.4558x; 1.0203x over previous
//
#include <hip/hip_runtime.h>

#define EDIM 1024
#define NHEADS 16
#define HDIM 64
#define SEQ 2048
#define BATCH 4
#define MROWS (BATCH * SEQ)   // 8192
#define NQKV (3 * EDIM)       // 3072
#define QKB 2048              // QK buffer row stride (Q cols 0..1023, K 1024..2047)

typedef __attribute__((ext_vector_type(4))) float f32x4;
typedef __attribute__((ext_vector_type(8))) short s16x8;
typedef __attribute__((ext_vector_type(4))) short s16x4;
typedef __attribute__((ext_vector_type(4))) unsigned int u32x4;

#define AS1 __attribute__((address_space(1)))
#define AS3 __attribute__((address_space(3)))
#define GLOAD_LDS16(g, l) __builtin_amdgcn_global_load_lds( \
    (AS1 void*)(void*)(g), (AS3 void*)(void*)(l), 16, 0, 0)

static __device__ __forceinline__ unsigned short f2bf(float f) {
  unsigned int u = __builtin_bit_cast(unsigned int, f);
  u += 0x7fffu + ((u >> 16) & 1u);   // RNE
  return (unsigned short)(u >> 16);
}

static __device__ __forceinline__ float fexp2(float x) {
  float r;
  asm("v_exp_f32 %0, %1" : "=v"(r) : "v"(x));
  return r;
}

static __device__ __forceinline__ unsigned int cvtpk(float a, float b) {
  unsigned int r;
  asm("v_cvt_pk_bf16_f32 %0, %1, %2" : "=v"(r) : "v"(a), "v"(b));
  return r;
}

static __device__ __forceinline__ f32x4 mfma_bf16(s16x8 a, s16x8 b, f32x4 c) {
  return __builtin_amdgcn_mfma_f32_16x16x32_bf16(a, b, c, 0, 0, 0);
}

// counted waitcnt with compile-time literal
template <int N>
static __device__ __forceinline__ void wait_vm() {
  if constexpr (N >= 8)      asm volatile("s_waitcnt lgkmcnt(0) vmcnt(8)" ::: "memory");
  else if constexpr (N == 6) asm volatile("s_waitcnt lgkmcnt(0) vmcnt(6)" ::: "memory");
  else if constexpr (N == 4) asm volatile("s_waitcnt lgkmcnt(0) vmcnt(4)" ::: "memory");
  else if constexpr (N == 3) asm volatile("s_waitcnt lgkmcnt(0) vmcnt(3)" ::: "memory");
  else if constexpr (N == 2) asm volatile("s_waitcnt lgkmcnt(0) vmcnt(2)" ::: "memory");
  else                       asm volatile("s_waitcnt lgkmcnt(0) vmcnt(0)" ::: "memory");
}

// one kernel converts x, w_qkv, w_proj (outputs contiguous in workspace)
__global__ void __launch_bounds__(256) cvt_all(const float* __restrict__ x,
                                               const float* __restrict__ wq,
                                               const float* __restrict__ wp,
                                               unsigned short* __restrict__ out) {
  const int i = blockIdx.x * 256 + threadIdx.x;   // float4 index
  const float* src;
  int j;
  if (i < 2097152) { src = x;  j = i; }
  else if (i < 2883584) { src = wq; j = i - 2097152; }
  else { src = wp; j = i - 2883584; }
  const float4 v = ((const float4*)src)[j];
  ushort4 o;
  o.x = f2bf(v.x); o.y = f2bf(v.y); o.z = f2bf(v.z); o.w = f2bf(v.w);
  ((ushort4*)out)[i] = o;
}

// ---------------------------------------------------------------------------
// 8-phase deep-pipelined GEMM (round-14, verified).
// MODE 2 (V^T) now stores with the kv-index low-5-bit permutation
//   s5 = j2*16 + g*4 + j1  ->  p5 = g*8 + j2*4 + j1
// so attention's PV B-fragment is contiguous (single ds_read_b128).
// ---------------------------------------------------------------------------
template <int MODE, int BMP, int BNP>
__global__ void __launch_bounds__(512, 2) gemm8p(const unsigned short* __restrict__ Ap,
                                                 const unsigned short* __restrict__ Bp,
                                                 const float* __restrict__ bias,
                                                 void* __restrict__ Cout,
                                                 int M, int N, int K) {
  extern __shared__ unsigned short lds[];
  constexpr int AHALF = BMP * 4096;   // u16: (BMP*64) rows x 64 cols
  constexpr int BHALF = BNP * 4096;
  constexpr int BBASE = 4 * AHALF;    // A region = 2 buf x 2 half

  const int tid = threadIdx.x;
  const int lane = tid & 63;
  const int wave = tid >> 6;        // 0..7
  const int wr = wave >> 2;         // 0..1  (M half)
  const int wc = wave & 3;          // 0..3  (N quarter)
  const int lr = lane & 15, kg = lane >> 4;

  const int nwg = gridDim.x;        // divisible by 8
  const int q8 = nwg >> 3;
  const int wgid = (blockIdx.x & 7) * q8 + (blockIdx.x >> 3);  // XCD-bijective
  const int NBM = M >> (BMP == 2 ? 8 : 7);
  const long m0 = (long)(wgid % NBM) * (BMP * 128);
  const long n0 = (long)(wgid / NBM) * (BNP * 128);

#define SA(buf, half, kt) do {                                                  \
    _Pragma("unroll")                                                           \
    for (int i_ = 0; i_ < BMP; ++i_) {                                          \
      const int rh_ = i_ * 64 + wave * 8 + (lane >> 3);                         \
      const int ce_ = ((lane & 7) ^ (lane >> 3)) * 8;                           \
      GLOAD_LDS16(Ap + (m0 + (half) * (BMP * 64) + rh_) * K + (kt) * 64 + ce_,  \
                  &lds[(buf) * 2 * AHALF + (half) * AHALF + i_ * 4096 + wave * 512]); \
    } } while (0)
#define SB(buf, half, kt) do {                                                  \
    _Pragma("unroll")                                                           \
    for (int i_ = 0; i_ < BNP; ++i_) {                                          \
      const int rh_ = i_ * 64 + wave * 8 + (lane >> 3);                         \
      const int ce_ = ((lane & 7) ^ (lane >> 3)) * 8;                           \
      GLOAD_LDS16(Bp + (n0 + (half) * (BNP * 64) + rh_) * K + (kt) * 64 + ce_,  \
                  &lds[BBASE + (buf) * 2 * BHALF + (half) * BHALF + i_ * 4096 + wave * 512]); \
    } } while (0)

#define PH_ENTER() do { __builtin_amdgcn_s_barrier();                           \
    asm volatile("s_waitcnt lgkmcnt(0)" ::: "memory");                          \
    __builtin_amdgcn_sched_barrier(0); } while (0)
#define PH_EXIT() __builtin_amdgcn_s_barrier()
#define PH_EXIT_VM() do { wait_vm<2 * BNP>();                                   \
    __builtin_amdgcn_sched_barrier(0);                                          \
    __builtin_amdgcn_s_barrier(); } while (0)
#define PH_EXIT_VM0() do { wait_vm<0>();                                        \
    __builtin_amdgcn_sched_barrier(0);                                          \
    __builtin_amdgcn_s_barrier(); } while (0)

  f32x4 acc[BMP * 4][BNP * 2] = {};
  s16x8 af[2 * BMP][2], bf0[BNP][2], bf1[BNP][2];

  auto LA = [&](int buf, int qm) {
#pragma unroll
    for (int m = 0; m < 2 * BMP; ++m) {
      const int rh = qm * (BMP * 32) + m * 16 + lr;
      const int ro = (buf * 2 + wr) * AHALF + rh * 64;
#pragma unroll
      for (int ks = 0; ks < 2; ++ks)
        af[m][ks] = *(const s16x8*)
            &lds[ro + (((ks * 64 + kg * 16) ^ ((rh & 7) << 4)) >> 1)];
    }
  };
  auto LB = [&](int buf, int qn, s16x8 (&bf)[BNP][2]) {
#pragma unroll
    for (int n = 0; n < BNP; ++n) {
      const int rh = (wc & 1) * (BNP * 32) + qn * (BNP * 16) + n * 16 + lr;
      const int ro = BBASE + (buf * 2 + (wc >> 1)) * BHALF + rh * 64;
#pragma unroll
      for (int ks = 0; ks < 2; ++ks)
        bf[n][ks] = *(const s16x8*)
            &lds[ro + (((ks * 64 + kg * 16) ^ ((rh & 7) << 4)) >> 1)];
    }
  };
  auto MM = [&](int qm, int qn, s16x8 (&bf)[BNP][2]) {
    __builtin_amdgcn_s_setprio(1);
#pragma unroll
    for (int m = 0; m < 2 * BMP; ++m)
#pragma unroll
      for (int n = 0; n < BNP; ++n)
#pragma unroll
        for (int ks = 0; ks < 2; ++ks)
          acc[qm * 2 * BMP + m][qn * BNP + n] =
              mfma_bf16(af[m][ks], bf[n][ks], acc[qm * 2 * BMP + m][qn * BNP + n]);
    __builtin_amdgcn_s_setprio(0);
  };

  const int nk = K >> 6;      // 64-wide K tiles (16)
  const int nit = nk >> 1;    // 8 iterations, 2 K-tiles each

  SB(0, 0, 0); SB(0, 1, 0);
  SA(0, 0, 0); SA(0, 1, 0);
  SB(1, 0, 1); SB(1, 1, 1);
  wait_vm<2 * BNP>();
  __builtin_amdgcn_sched_barrier(0);
  __builtin_amdgcn_s_barrier();
  __builtin_amdgcn_sched_barrier(0);

  for (int it = 0; it < nit; ++it) {
    const int ta = 2 * it, tb = 2 * it + 1;
    LA(0, 0); LB(0, 0, bf0);
    SA(1, 0, tb);
    PH_ENTER(); MM(0, 0, bf0); PH_EXIT();
    LB(0, 1, bf1);
    SA(1, 1, tb);
    PH_ENTER(); MM(0, 1, bf1); PH_EXIT();
    LA(0, 1);
    if (ta + 2 < nk) SB(0, 0, ta + 2);
    PH_ENTER(); MM(1, 0, bf0); PH_EXIT();
    if (ta + 2 < nk) SB(0, 1, ta + 2);
    PH_ENTER(); MM(1, 1, bf1);
    if (it + 1 < nit) { PH_EXIT_VM(); } else { PH_EXIT_VM0(); }
    LA(1, 0); LB(1, 0, bf0);
    if (ta + 2 < nk) SA(0, 0, ta + 2);
    PH_ENTER(); MM(0, 0, bf0); PH_EXIT();
    LB(1, 1, bf1);
    if (ta + 2 < nk) SA(0, 1, ta + 2);
    PH_ENTER(); MM(0, 1, bf1); PH_EXIT();
    LA(1, 1);
    if (tb + 2 < nk) SB(1, 0, tb + 2);
    PH_ENTER(); MM(1, 0, bf0); PH_EXIT();
    if (tb + 2 < nk) SB(1, 1, tb + 2);
    PH_ENTER(); MM(1, 1, bf1); PH_EXIT_VM();
  }

#pragma unroll
  for (int nt = 0; nt < BNP * 2; ++nt) {
    const long col = n0 + wc * (BNP * 32) + nt * 16 + lr;
    const float bv = (MODE == 2) ? 0.f : bias[col];
#pragma unroll
    for (int mt = 0; mt < BMP * 4; ++mt) {
#pragma unroll
      for (int r = 0; r < 4; ++r) {
        const long row = m0 + wr * (BMP * 64) + mt * 16 + kg * 4 + r;
        if (MODE == 0) {
          float v = acc[mt][nt][r] + bv;
          if (col < EDIM) v *= 0.18033688011112042f;  // 0.125 * log2(e)
          ((unsigned short*)Cout)[row * QKB + col] = f2bf(v);
        } else if (MODE == 1) {
          ((float*)Cout)[row * N + col] = acc[mt][nt][r] + bv;
        } else {
          // V^T store with kv low-5-bit permutation (attn PV b128 layout):
          // s5 = j2*16+g*4+j1 -> p5 = g*8+j2*4+j1
          const float v = acc[mt][nt][r] + bias[row];
          const int base = (int)(col & 2047);
          const int s5 = base & 31;
          const int p5 = ((s5 >> 2) & 3) * 8 + ((s5 >> 4) & 1) * 4 + (s5 & 3);
          const int sperm = (base & ~31) | p5;
          ((unsigned short*)Cout)[((col >> 11) * 1024 + row) * (long)2048 +
                                  sperm] = f2bf(v);
        }
      }
    }
  }
#undef SA
#undef SB
#undef PH_ENTER
#undef PH_EXIT
#undef PH_EXIT_VM
#undef PH_EXIT_VM0
}

// ---------------------------------------------------------------------------
// Flash attention — r19 pair-unrolled shell; V^T is kv-permuted in global
// memory so the PV B-fragment is ONE ds_read_b128 (was 2x b64 + shuffle).
// Read block index (4kc+kg) ^ (d&7): same proven conflict-free pattern as K.
// ---------------------------------------------------------------------------
__global__ void __launch_bounds__(512, 4) attn_fwd(const unsigned short* __restrict__ qk,
                                                   const unsigned short* __restrict__ vT,
                                                   unsigned short* __restrict__ attout) {
  const int L = blockIdx.x;
  const int bh = (L & 7) * 8 + (L >> 6);
  const int qt = (L >> 3) & 7;
  const int b = bh >> 4, h = bh & 15;
  const int q0 = qt * 256;
  const int tid = threadIdx.x, lane = tid & 63, wave = tid >> 6;  // wave 0..7
  const int lr = lane & 15, kg = lane >> 4;

  __shared__ unsigned short Ks[4][4096];   // [slot][k 64][d 64] swizzled
  __shared__ unsigned short Vs[4][4096];   // [slot][d 64][kv 64] permuted+swizzled

  const long rowbase = (long)b * SEQ;

#define ASTAGE(slot, kv0) do {                                                  \
    const int row_ = wave * 8 + (lane >> 3);                                    \
    const int col_ = ((lane & 7) ^ (lane >> 3)) << 3;                           \
    GLOAD_LDS16(qk + (rowbase + (kv0) + row_) * QKB + EDIM + h * HDIM + col_,   \
                &Ks[slot][wave * 512]);                                         \
    GLOAD_LDS16(vT + ((long)bh * HDIM + row_) * SEQ + (kv0) + col_,             \
                &Vs[slot][wave * 512]);                                         \
  } while (0)

  // full per-tile body: QK^T (log2 domain) -> exp/rowsum/pack -> PV
#define TILE_BODY(T) do {                                                       \
    const unsigned short* Kb_ = Ks[(T) & 3];                                    \
    const unsigned short* Vb_ = Vs[(T) & 3];                                    \
    f32x4 st[2][4];                                                             \
    __builtin_amdgcn_s_setprio(1);                                              \
    _Pragma("unroll")                                                           \
    for (int ct = 0; ct < 4; ++ct) {                                            \
      const int rb_ = (ct * 16 + lr) * 128;                                     \
      const int sw_ = (lr & 7) << 4;                                            \
      const s16x8 k0_ = *(const s16x8*)&Kb_[(rb_ + ((kg * 16) ^ sw_)) >> 1];    \
      const s16x8 k1_ = *(const s16x8*)&Kb_[(rb_ + ((64 + kg * 16) ^ sw_)) >> 1];\
      _Pragma("unroll")                                                         \
      for (int qs = 0; qs < 2; ++qs) {                                          \
        f32x4 a_ = {};                                                          \
        a_ = mfma_bf16(k0_, qf[qs][0], a_);                                     \
        a_ = mfma_bf16(k1_, qf[qs][1], a_);                                     \
        st[qs][ct] = a_;                                                        \
      }                                                                         \
    }                                                                           \
    __builtin_amdgcn_s_setprio(0);                                              \
    unsigned int pk[2][4][2];                                                   \
    _Pragma("unroll")                                                           \
    for (int qs = 0; qs < 2; ++qs) {                                            \
      f32x4 rv_ = {0.f, 0.f, 0.f, 0.f};                                         \
      _Pragma("unroll")                                                         \
      for (int ct = 0; ct < 4; ++ct) {                                          \
        f32x4 p_;                                                               \
        _Pragma("unroll")                                                       \
        for (int r = 0; r < 4; ++r) p_[r] = fexp2(st[qs][ct][r]);               \
        rv_ += p_;                                                              \
        pk[qs][ct][0] = cvtpk(p_[0], p_[1]);                                    \
        pk[qs][ct][1] = cvtpk(p_[2], p_[3]);                                    \
      }                                                                         \
      l_part[qs] += rv_;                                                        \
    }                                                                           \
    _Pragma("unroll")                                                           \
    for (int kc = 0; kc < 2; ++kc) {                                            \
      s16x8 pa_[2];                                                             \
      _Pragma("unroll")                                                         \
      for (int qs = 0; qs < 2; ++qs) {                                          \
        u32x4 wv_ = {pk[qs][2 * kc][0], pk[qs][2 * kc][1],                      \
                     pk[qs][2 * kc + 1][0], pk[qs][2 * kc + 1][1]};             \
        pa_[qs] = __builtin_bit_cast(s16x8, wv_);                               \
      }                                                                         \
      __builtin_amdgcn_s_setprio(1);                                            \
      _Pragma("unroll")                                                         \
      for (int dt = 0; dt < 4; ++dt) {                                          \
        const int rb_ = (dt * 16 + lr) * 128;                                   \
        const int c0_ = (64 * kc + 16 * kg) ^ ((lr & 7) << 4);                  \
        const s16x8 vf_ = *(const s16x8*)&Vb_[(rb_ + c0_) >> 1];                \
        _Pragma("unroll")                                                       \
        for (int qs = 0; qs < 2; ++qs)                                          \
          o_acc[qs][dt] = mfma_bf16(pa_[qs], vf_, o_acc[qs][dt]);               \
      }                                                                         \
      __builtin_amdgcn_s_setprio(0);                                            \
    }                                                                           \
  } while (0)

  s16x8 qf[2][2];
#pragma unroll
  for (int qs = 0; qs < 2; ++qs) {
    const unsigned short* qp =
        qk + (rowbase + q0 + wave * 32 + qs * 16 + lr) * QKB + h * HDIM + kg * 8;
    qf[qs][0] = *(const s16x8*)qp;
    qf[qs][1] = *(const s16x8*)(qp + 32);
  }

  f32x4 l_part[2] = {{0.f, 0.f, 0.f, 0.f}, {0.f, 0.f, 0.f, 0.f}};
  f32x4 o_acc[2][4] = {};

  // prologue: pair 0 staged and landed
  ASTAGE(0, 0); ASTAGE(1, 64);
  wait_vm<0>();
  __builtin_amdgcn_s_barrier();
  __builtin_amdgcn_sched_barrier(0);

  for (int p = 0; p < 16; ++p) {
    const int t0 = 2 * p;
    if (p + 1 < 16) {   // stage next pair early — latency hidden by 2 bodies
      ASTAGE((t0 + 2) & 3, (t0 + 2) * 64);
      ASTAGE((t0 + 3) & 3, (t0 + 3) * 64);
    }
    TILE_BODY(t0);
    TILE_BODY(t0 + 1);
    wait_vm<0>();       // next pair landed (issued ~2 bodies ago)
    __builtin_amdgcn_s_barrier();
    __builtin_amdgcn_sched_barrier(0);
  }

#pragma unroll
  for (int qs = 0; qs < 2; ++qs) {
    float rs = (l_part[qs][0] + l_part[qs][1]) + (l_part[qs][2] + l_part[qs][3]);
    rs += __shfl_xor(rs, 16, 64);
    rs += __shfl_xor(rs, 32, 64);
#pragma unroll
    for (int r = 0; r < 4; ++r) {
      const float lq = __shfl(rs, kg * 4 + r, 64);
      const float inv = 1.0f / lq;
      const long row = rowbase + q0 + wave * 32 + qs * 16 + kg * 4 + r;
#pragma unroll
      for (int dt = 0; dt < 4; ++dt)
        attout[row * EDIM + h * HDIM + dt * 16 + lr] = f2bf(o_acc[qs][dt][r] * inv);
    }
  }
#undef ASTAGE
#undef TILE_BODY
}

extern "C" void kernel_launch(void* const* d_in, const int* in_sizes, int n_in,
                              void* d_out, int out_size, void* d_ws, size_t ws_size,
                              hipStream_t stream) {
  const float* x      = (const float*)d_in[0];
  const float* w_qkv  = (const float*)d_in[1];
  const float* b_qkv  = (const float*)d_in[2];
  const float* w_proj = (const float*)d_in[3];
  const float* b_proj = (const float*)d_in[4];

  unsigned short* xb   = (unsigned short*)d_ws;              // 8.39M elems
  unsigned short* wqb  = xb   + (size_t)MROWS * EDIM;        // 3.15M
  unsigned short* wpb  = wqb  + (size_t)NQKV * EDIM;         // 1.05M
  unsigned short* qkb  = wpb  + (size_t)EDIM * EDIM;         // 16.8M ([8192][2048])
  unsigned short* attb = qkb  + (size_t)MROWS * QKB;         // 8.39M
  unsigned short* vTb  = attb + (size_t)MROWS * EDIM;        // 8.39M (permuted V^T)

  const int sh22 = 131072;  // (2+2) x 32KB
  const int sh12 = 98304;   // (1+2) x 32KB
  const int sh21 = 98304;   // (2+1) x 32KB
  hipFuncSetAttribute((const void*)gemm8p<0, 2, 2>,
                      hipFuncAttributeMaxDynamicSharedMemorySize, sh22);
  hipFuncSetAttribute((const void*)gemm8p<2, 1, 2>,
                      hipFuncAttributeMaxDynamicSharedMemorySize, sh12);
  hipFuncSetAttribute((const void*)gemm8p<1, 2, 1>,
                      hipFuncAttributeMaxDynamicSharedMemorySize, sh21);

  cvt_all<<<12288, 256, 0, stream>>>(x, w_qkv, w_proj, xb);

  // QK projection: [8192][2048] (Q pre-scaled into log2 domain). 256 wgs.
  gemm8p<0, 2, 2><<<(MROWS / 256) * (QKB / 256), 512, sh22, stream>>>(
      xb, wqb, b_qkv, qkb, MROWS, QKB, EDIM);

  // V^T directly (swapped operands; kv-permuted scattered store). 128x256 tile.
  gemm8p<2, 1, 2><<<(EDIM / 128) * (MROWS / 256), 512, sh12, stream>>>(
      wqb + (size_t)2048 * EDIM, xb, b_qkv + 2048, vTb, EDIM, MROWS, EDIM);

  attn_fwd<<<512, 512, 0, stream>>>(qkb, vTb, attb);

  // proj: 256x128 tile.
  gemm8p<1, 2, 1><<<(MROWS / 256) * (EDIM / 128), 512, sh21, stream>>>(
      attb, wpb, b_proj, d_out, MROWS, EDIM, EDIM);
}

// Round 21
// 172.717 us; speedup vs baseline: 4.6553x; 1.0448x over previous
//
#include <hip/hip_runtime.h>

#define EDIM 1024
#define NHEADS 16
#define HDIM 64
#define SEQ 2048
#define BATCH 4
#define MROWS (BATCH * SEQ)   // 8192
#define NQKV (3 * EDIM)       // 3072
#define QKB 2048              // QK buffer row stride (Q cols 0..1023, K 1024..2047)

typedef __attribute__((ext_vector_type(4))) float f32x4;
typedef __attribute__((ext_vector_type(8))) short s16x8;
typedef __attribute__((ext_vector_type(4))) short s16x4;
typedef __attribute__((ext_vector_type(4))) unsigned int u32x4;

#define AS1 __attribute__((address_space(1)))
#define AS3 __attribute__((address_space(3)))
#define GLOAD_LDS16(g, l) __builtin_amdgcn_global_load_lds( \
    (AS1 void*)(void*)(g), (AS3 void*)(void*)(l), 16, 0, 0)

static __device__ __forceinline__ unsigned short f2bf(float f) {
  unsigned int u = __builtin_bit_cast(unsigned int, f);
  u += 0x7fffu + ((u >> 16) & 1u);   // RNE
  return (unsigned short)(u >> 16);
}

static __device__ __forceinline__ float fexp2(float x) {
  float r;
  asm("v_exp_f32 %0, %1" : "=v"(r) : "v"(x));
  return r;
}

static __device__ __forceinline__ unsigned int cvtpk(float a, float b) {
  unsigned int r;
  asm("v_cvt_pk_bf16_f32 %0, %1, %2" : "=v"(r) : "v"(a), "v"(b));
  return r;
}

static __device__ __forceinline__ f32x4 mfma_bf16(s16x8 a, s16x8 b, f32x4 c) {
  return __builtin_amdgcn_mfma_f32_16x16x32_bf16(a, b, c, 0, 0, 0);
}

// counted waitcnt with compile-time literal
template <int N>
static __device__ __forceinline__ void wait_vm() {
  if constexpr (N >= 8)      asm volatile("s_waitcnt lgkmcnt(0) vmcnt(8)" ::: "memory");
  else if constexpr (N == 6) asm volatile("s_waitcnt lgkmcnt(0) vmcnt(6)" ::: "memory");
  else if constexpr (N == 4) asm volatile("s_waitcnt lgkmcnt(0) vmcnt(4)" ::: "memory");
  else if constexpr (N == 3) asm volatile("s_waitcnt lgkmcnt(0) vmcnt(3)" ::: "memory");
  else if constexpr (N == 2) asm volatile("s_waitcnt lgkmcnt(0) vmcnt(2)" ::: "memory");
  else                       asm volatile("s_waitcnt lgkmcnt(0) vmcnt(0)" ::: "memory");
}

// XCD-bijective swizzle for a 256-block (sub-)grid
static __device__ __forceinline__ int swz256(int bid) {
  return (bid & 7) * 32 + (bid >> 3);
}

// one kernel converts x, w_qkv, w_proj (outputs contiguous in workspace)
__global__ void __launch_bounds__(256) cvt_all(const float* __restrict__ x,
                                               const float* __restrict__ wq,
                                               const float* __restrict__ wp,
                                               unsigned short* __restrict__ out) {
  const int i = blockIdx.x * 256 + threadIdx.x;   // float4 index
  const float* src;
  int j;
  if (i < 2097152) { src = x;  j = i; }
  else if (i < 2883584) { src = wq; j = i - 2097152; }
  else { src = wp; j = i - 2883584; }
  const float4 v = ((const float4*)src)[j];
  ushort4 o;
  o.x = f2bf(v.x); o.y = f2bf(v.y); o.z = f2bf(v.z); o.w = f2bf(v.w);
  ((ushort4*)out)[i] = o;
}

// ---------------------------------------------------------------------------
// 8-phase deep-pipelined GEMM body (round-14 schedule, verified), factored as
// a device function so independent GEMMs can share one dispatch.
// MODE 0: QK epilogue; MODE 1: proj (f32); MODE 2: V^T kv-permuted store.
// ---------------------------------------------------------------------------
template <int MODE, int BMP, int BNP>
static __device__ __forceinline__ void gemm8p_body(
    const unsigned short* __restrict__ Ap, const unsigned short* __restrict__ Bp,
    const float* __restrict__ bias, void* __restrict__ Cout,
    int M, int N, int K, int wgid, unsigned short* lds) {
  constexpr int AHALF = BMP * 4096;   // u16: (BMP*64) rows x 64 cols
  constexpr int BHALF = BNP * 4096;
  constexpr int BBASE = 4 * AHALF;    // A region = 2 buf x 2 half

  const int tid = threadIdx.x;
  const int lane = tid & 63;
  const int wave = tid >> 6;        // 0..7
  const int wr = wave >> 2;         // 0..1  (M half)
  const int wc = wave & 3;          // 0..3  (N quarter)
  const int lr = lane & 15, kg = lane >> 4;

  const int NBM = M >> (BMP == 2 ? 8 : 7);
  const long m0 = (long)(wgid % NBM) * (BMP * 128);
  const long n0 = (long)(wgid / NBM) * (BNP * 128);

#define SA(buf, half, kt) do {                                                  \
    _Pragma("unroll")                                                           \
    for (int i_ = 0; i_ < BMP; ++i_) {                                          \
      const int rh_ = i_ * 64 + wave * 8 + (lane >> 3);                         \
      const int ce_ = ((lane & 7) ^ (lane >> 3)) * 8;                           \
      GLOAD_LDS16(Ap + (m0 + (half) * (BMP * 64) + rh_) * K + (kt) * 64 + ce_,  \
                  &lds[(buf) * 2 * AHALF + (half) * AHALF + i_ * 4096 + wave * 512]); \
    } } while (0)
#define SB(buf, half, kt) do {                                                  \
    _Pragma("unroll")                                                           \
    for (int i_ = 0; i_ < BNP; ++i_) {                                          \
      const int rh_ = i_ * 64 + wave * 8 + (lane >> 3);                         \
      const int ce_ = ((lane & 7) ^ (lane >> 3)) * 8;                           \
      GLOAD_LDS16(Bp + (n0 + (half) * (BNP * 64) + rh_) * K + (kt) * 64 + ce_,  \
                  &lds[BBASE + (buf) * 2 * BHALF + (half) * BHALF + i_ * 4096 + wave * 512]); \
    } } while (0)

#define PH_ENTER() do { __builtin_amdgcn_s_barrier();                           \
    asm volatile("s_waitcnt lgkmcnt(0)" ::: "memory");                          \
    __builtin_amdgcn_sched_barrier(0); } while (0)
#define PH_EXIT() __builtin_amdgcn_s_barrier()
#define PH_EXIT_VM() do { wait_vm<2 * BNP>();                                   \
    __builtin_amdgcn_sched_barrier(0);                                          \
    __builtin_amdgcn_s_barrier(); } while (0)
#define PH_EXIT_VM0() do { wait_vm<0>();                                        \
    __builtin_amdgcn_sched_barrier(0);                                          \
    __builtin_amdgcn_s_barrier(); } while (0)

  f32x4 acc[BMP * 4][BNP * 2] = {};
  s16x8 af[2 * BMP][2], bf0[BNP][2], bf1[BNP][2];

  auto LA = [&](int buf, int qm) {
#pragma unroll
    for (int m = 0; m < 2 * BMP; ++m) {
      const int rh = qm * (BMP * 32) + m * 16 + lr;
      const int ro = (buf * 2 + wr) * AHALF + rh * 64;
#pragma unroll
      for (int ks = 0; ks < 2; ++ks)
        af[m][ks] = *(const s16x8*)
            &lds[ro + (((ks * 64 + kg * 16) ^ ((rh & 7) << 4)) >> 1)];
    }
  };
  auto LB = [&](int buf, int qn, s16x8 (&bf)[BNP][2]) {
#pragma unroll
    for (int n = 0; n < BNP; ++n) {
      const int rh = (wc & 1) * (BNP * 32) + qn * (BNP * 16) + n * 16 + lr;
      const int ro = BBASE + (buf * 2 + (wc >> 1)) * BHALF + rh * 64;
#pragma unroll
      for (int ks = 0; ks < 2; ++ks)
        bf[n][ks] = *(const s16x8*)
            &lds[ro + (((ks * 64 + kg * 16) ^ ((rh & 7) << 4)) >> 1)];
    }
  };
  auto MM = [&](int qm, int qn, s16x8 (&bf)[BNP][2]) {
    __builtin_amdgcn_s_setprio(1);
#pragma unroll
    for (int m = 0; m < 2 * BMP; ++m)
#pragma unroll
      for (int n = 0; n < BNP; ++n)
#pragma unroll
        for (int ks = 0; ks < 2; ++ks)
          acc[qm * 2 * BMP + m][qn * BNP + n] =
              mfma_bf16(af[m][ks], bf[n][ks], acc[qm * 2 * BMP + m][qn * BNP + n]);
    __builtin_amdgcn_s_setprio(0);
  };

  const int nk = K >> 6;      // 64-wide K tiles (16)
  const int nit = nk >> 1;    // 8 iterations, 2 K-tiles each

  SB(0, 0, 0); SB(0, 1, 0);
  SA(0, 0, 0); SA(0, 1, 0);
  SB(1, 0, 1); SB(1, 1, 1);
  wait_vm<2 * BNP>();
  __builtin_amdgcn_sched_barrier(0);
  __builtin_amdgcn_s_barrier();
  __builtin_amdgcn_sched_barrier(0);

  for (int it = 0; it < nit; ++it) {
    const int ta = 2 * it, tb = 2 * it + 1;
    LA(0, 0); LB(0, 0, bf0);
    SA(1, 0, tb);
    PH_ENTER(); MM(0, 0, bf0); PH_EXIT();
    LB(0, 1, bf1);
    SA(1, 1, tb);
    PH_ENTER(); MM(0, 1, bf1); PH_EXIT();
    LA(0, 1);
    if (ta + 2 < nk) SB(0, 0, ta + 2);
    PH_ENTER(); MM(1, 0, bf0); PH_EXIT();
    if (ta + 2 < nk) SB(0, 1, ta + 2);
    PH_ENTER(); MM(1, 1, bf1);
    if (it + 1 < nit) { PH_EXIT_VM(); } else { PH_EXIT_VM0(); }
    LA(1, 0); LB(1, 0, bf0);
    if (ta + 2 < nk) SA(0, 0, ta + 2);
    PH_ENTER(); MM(0, 0, bf0); PH_EXIT();
    LB(1, 1, bf1);
    if (ta + 2 < nk) SA(0, 1, ta + 2);
    PH_ENTER(); MM(0, 1, bf1); PH_EXIT();
    LA(1, 1);
    if (tb + 2 < nk) SB(1, 0, tb + 2);
    PH_ENTER(); MM(1, 0, bf0); PH_EXIT();
    if (tb + 2 < nk) SB(1, 1, tb + 2);
    PH_ENTER(); MM(1, 1, bf1); PH_EXIT_VM();
  }

#pragma unroll
  for (int nt = 0; nt < BNP * 2; ++nt) {
    const long col = n0 + wc * (BNP * 32) + nt * 16 + lr;
    const float bv = (MODE == 2) ? 0.f : bias[col];
#pragma unroll
    for (int mt = 0; mt < BMP * 4; ++mt) {
#pragma unroll
      for (int r = 0; r < 4; ++r) {
        const long row = m0 + wr * (BMP * 64) + mt * 16 + kg * 4 + r;
        if (MODE == 0) {
          float v = acc[mt][nt][r] + bv;
          if (col < EDIM) v *= 0.18033688011112042f;  // 0.125 * log2(e)
          ((unsigned short*)Cout)[row * QKB + col] = f2bf(v);
        } else if (MODE == 1) {
          ((float*)Cout)[row * N + col] = acc[mt][nt][r] + bv;
        } else {
          // V^T store with kv low-5-bit permutation (attn PV b128 layout):
          // s5 = j2*16+g*4+j1 -> p5 = g*8+j2*4+j1
          const float v = acc[mt][nt][r] + bias[row];
          const int base = (int)(col & 2047);
          const int s5 = base & 31;
          const int p5 = ((s5 >> 2) & 3) * 8 + ((s5 >> 4) & 1) * 4 + (s5 & 3);
          const int sperm = (base & ~31) | p5;
          ((unsigned short*)Cout)[((col >> 11) * 1024 + row) * (long)2048 +
                                  sperm] = f2bf(v);
        }
      }
    }
  }
#undef SA
#undef SB
#undef PH_ENTER
#undef PH_EXIT
#undef PH_EXIT_VM
#undef PH_EXIT_VM0
}

// Fused dispatch: blocks 0..255 compute the QK projection, 256..511 compute
// V^T. Independent outputs; V^T backfills CUs as QK blocks retire (tail fill).
__global__ void __launch_bounds__(512, 2) gemm_qk_vt(
    const unsigned short* __restrict__ xb, const unsigned short* __restrict__ wqb,
    const float* __restrict__ b_qkv,
    unsigned short* __restrict__ qkb, unsigned short* __restrict__ vTb) {
  extern __shared__ unsigned short lds[];
  const int bid = blockIdx.x;
  if (bid < 256) {
    gemm8p_body<0, 2, 2>(xb, wqb, b_qkv, qkb, MROWS, QKB, EDIM,
                         swz256(bid), lds);
  } else {
    gemm8p_body<2, 1, 2>(wqb + (size_t)2048 * EDIM, xb, b_qkv + 2048, vTb,
                         EDIM, MROWS, EDIM, swz256(bid - 256), lds);
  }
}

__global__ void __launch_bounds__(512, 2) gemm_proj(
    const unsigned short* __restrict__ attb, const unsigned short* __restrict__ wpb,
    const float* __restrict__ b_proj, float* __restrict__ out) {
  extern __shared__ unsigned short lds[];
  gemm8p_body<1, 2, 1>(attb, wpb, b_proj, out, MROWS, EDIM, EDIM,
                       swz256((int)blockIdx.x), lds);
}

// ---------------------------------------------------------------------------
// Flash attention — r20 configuration (verified: 77.9 µs, 0 bank conflicts).
// Pair-unrolled 4-slot counted-vmcnt shell; V^T kv-permuted in global memory
// so the PV B-fragment is one ds_read_b128.
// ---------------------------------------------------------------------------
__global__ void __launch_bounds__(512, 4) attn_fwd(const unsigned short* __restrict__ qk,
                                                   const unsigned short* __restrict__ vT,
                                                   unsigned short* __restrict__ attout) {
  const int L = blockIdx.x;
  const int bh = (L & 7) * 8 + (L >> 6);
  const int qt = (L >> 3) & 7;
  const int b = bh >> 4, h = bh & 15;
  const int q0 = qt * 256;
  const int tid = threadIdx.x, lane = tid & 63, wave = tid >> 6;  // wave 0..7
  const int lr = lane & 15, kg = lane >> 4;

  __shared__ unsigned short Ks[4][4096];   // [slot][k 64][d 64] swizzled
  __shared__ unsigned short Vs[4][4096];   // [slot][d 64][kv 64] permuted+swizzled

  const long rowbase = (long)b * SEQ;

#define ASTAGE(slot, kv0) do {                                                  \
    const int row_ = wave * 8 + (lane >> 3);                                    \
    const int col_ = ((lane & 7) ^ (lane >> 3)) << 3;                           \
    GLOAD_LDS16(qk + (rowbase + (kv0) + row_) * QKB + EDIM + h * HDIM + col_,   \
                &Ks[slot][wave * 512]);                                         \
    GLOAD_LDS16(vT + ((long)bh * HDIM + row_) * SEQ + (kv0) + col_,             \
                &Vs[slot][wave * 512]);                                         \
  } while (0)

#define TILE_BODY(T) do {                                                       \
    const unsigned short* Kb_ = Ks[(T) & 3];                                    \
    const unsigned short* Vb_ = Vs[(T) & 3];                                    \
    f32x4 st[2][4];                                                             \
    __builtin_amdgcn_s_setprio(1);                                              \
    _Pragma("unroll")                                                           \
    for (int ct = 0; ct < 4; ++ct) {                                            \
      const int rb_ = (ct * 16 + lr) * 128;                                     \
      const int sw_ = (lr & 7) << 4;                                            \
      const s16x8 k0_ = *(const s16x8*)&Kb_[(rb_ + ((kg * 16) ^ sw_)) >> 1];    \
      const s16x8 k1_ = *(const s16x8*)&Kb_[(rb_ + ((64 + kg * 16) ^ sw_)) >> 1];\
      _Pragma("unroll")                                                         \
      for (int qs = 0; qs < 2; ++qs) {                                          \
        f32x4 a_ = {};                                                          \
        a_ = mfma_bf16(k0_, qf[qs][0], a_);                                     \
        a_ = mfma_bf16(k1_, qf[qs][1], a_);                                     \
        st[qs][ct] = a_;                                                        \
      }                                                                         \
    }                                                                           \
    __builtin_amdgcn_s_setprio(0);                                              \
    unsigned int pk[2][4][2];                                                   \
    _Pragma("unroll")                                                           \
    for (int qs = 0; qs < 2; ++qs) {                                            \
      f32x4 rv_ = {0.f, 0.f, 0.f, 0.f};                                         \
      _Pragma("unroll")                                                         \
      for (int ct = 0; ct < 4; ++ct) {                                          \
        f32x4 p_;                                                               \
        _Pragma("unroll")                                                       \
        for (int r = 0; r < 4; ++r) p_[r] = fexp2(st[qs][ct][r]);               \
        rv_ += p_;                                                              \
        pk[qs][ct][0] = cvtpk(p_[0], p_[1]);                                    \
        pk[qs][ct][1] = cvtpk(p_[2], p_[3]);                                    \
      }                                                                         \
      l_part[qs] += rv_;                                                        \
    }                                                                           \
    _Pragma("unroll")                                                           \
    for (int kc = 0; kc < 2; ++kc) {                                            \
      s16x8 pa_[2];                                                             \
      _Pragma("unroll")                                                         \
      for (int qs = 0; qs < 2; ++qs) {                                          \
        u32x4 wv_ = {pk[qs][2 * kc][0], pk[qs][2 * kc][1],                      \
                     pk[qs][2 * kc + 1][0], pk[qs][2 * kc + 1][1]};             \
        pa_[qs] = __builtin_bit_cast(s16x8, wv_);                               \
      }                                                                         \
      __builtin_amdgcn_s_setprio(1);                                            \
      _Pragma("unroll")                                                         \
      for (int dt = 0; dt < 4; ++dt) {                                          \
        const int rb_ = (dt * 16 + lr) * 128;                                   \
        const int c0_ = (64 * kc + 16 * kg) ^ ((lr & 7) << 4);                  \
        const s16x8 vf_ = *(const s16x8*)&Vb_[(rb_ + c0_) >> 1];                \
        _Pragma("unroll")                                                       \
        for (int qs = 0; qs < 2; ++qs)                                          \
          o_acc[qs][dt] = mfma_bf16(pa_[qs], vf_, o_acc[qs][dt]);               \
      }                                                                         \
      __builtin_amdgcn_s_setprio(0);                                            \
    }                                                                           \
  } while (0)

  s16x8 qf[2][2];
#pragma unroll
  for (int qs = 0; qs < 2; ++qs) {
    const unsigned short* qp =
        qk + (rowbase + q0 + wave * 32 + qs * 16 + lr) * QKB + h * HDIM + kg * 8;
    qf[qs][0] = *(const s16x8*)qp;
    qf[qs][1] = *(const s16x8*)(qp + 32);
  }

  f32x4 l_part[2] = {{0.f, 0.f, 0.f, 0.f}, {0.f, 0.f, 0.f, 0.f}};
  f32x4 o_acc[2][4] = {};

  // prologue: pair 0 staged and landed
  ASTAGE(0, 0); ASTAGE(1, 64);
  wait_vm<0>();
  __builtin_amdgcn_s_barrier();
  __builtin_amdgcn_sched_barrier(0);

  for (int p = 0; p < 16; ++p) {
    const int t0 = 2 * p;
    if (p + 1 < 16) {   // stage next pair early — latency hidden by 2 bodies
      ASTAGE((t0 + 2) & 3, (t0 + 2) * 64);
      ASTAGE((t0 + 3) & 3, (t0 + 3) * 64);
    }
    TILE_BODY(t0);
    TILE_BODY(t0 + 1);
    wait_vm<0>();       // next pair landed (issued ~2 bodies ago)
    __builtin_amdgcn_s_barrier();
    __builtin_amdgcn_sched_barrier(0);
  }

#pragma unroll
  for (int qs = 0; qs < 2; ++qs) {
    float rs = (l_part[qs][0] + l_part[qs][1]) + (l_part[qs][2] + l_part[qs][3]);
    rs += __shfl_xor(rs, 16, 64);
    rs += __shfl_xor(rs, 32, 64);
#pragma unroll
    for (int r = 0; r < 4; ++r) {
      const float lq = __shfl(rs, kg * 4 + r, 64);
      const float inv = 1.0f / lq;
      const long row = rowbase + q0 + wave * 32 + qs * 16 + kg * 4 + r;
#pragma unroll
      for (int dt = 0; dt < 4; ++dt)
        attout[row * EDIM + h * HDIM + dt * 16 + lr] = f2bf(o_acc[qs][dt][r] * inv);
    }
  }
#undef ASTAGE
#undef TILE_BODY
}

extern "C" void kernel_launch(void* const* d_in, const int* in_sizes, int n_in,
                              void* d_out, int out_size, void* d_ws, size_t ws_size,
                              hipStream_t stream) {
  const float* x      = (const float*)d_in[0];
  const float* w_qkv  = (const float*)d_in[1];
  const float* b_qkv  = (const float*)d_in[2];
  const float* w_proj = (const float*)d_in[3];
  const float* b_proj = (const float*)d_in[4];

  unsigned short* xb   = (unsigned short*)d_ws;              // 8.39M elems
  unsigned short* wqb  = xb   + (size_t)MROWS * EDIM;        // 3.15M
  unsigned short* wpb  = wqb  + (size_t)NQKV * EDIM;         // 1.05M
  unsigned short* qkb  = wpb  + (size_t)EDIM * EDIM;         // 16.8M ([8192][2048])
  unsigned short* attb = qkb  + (size_t)MROWS * QKB;         // 8.39M
  unsigned short* vTb  = attb + (size_t)MROWS * EDIM;        // 8.39M (permuted V^T)

  const int sh22 = 131072;  // max of QK (128KB) / V^T (96KB) paths
  const int sh21 = 98304;   // proj
  hipFuncSetAttribute((const void*)gemm_qk_vt,
                      hipFuncAttributeMaxDynamicSharedMemorySize, sh22);
  hipFuncSetAttribute((const void*)gemm_proj,
                      hipFuncAttributeMaxDynamicSharedMemorySize, sh21);

  cvt_all<<<12288, 256, 0, stream>>>(x, w_qkv, w_proj, xb);

  // QK projection (256 blocks) + V^T (256 blocks) fused: independent outputs,
  // tail-filled scheduling.
  gemm_qk_vt<<<512, 512, sh22, stream>>>(xb, wqb, b_qkv, qkb, vTb);

  attn_fwd<<<512, 512, 0, stream>>>(qkb, vTb, attb);

  gemm_proj<<<256, 512, sh21, stream>>>(attb, wpb, b_proj, (float*)d_out);
}

// Round 22
// 169.473 us; speedup vs baseline: 4.7444x; 1.0191x over previous
//
#include <hip/hip_runtime.h>

#define EDIM 1024
#define NHEADS 16
#define HDIM 64
#define SEQ 2048
#define BATCH 4
#define MROWS (BATCH * SEQ)   // 8192
#define NQKV (3 * EDIM)       // 3072
#define QKB 2048              // QK buffer row stride (Q cols 0..1023, K 1024..2047)

typedef __attribute__((ext_vector_type(4))) float f32x4;
typedef __attribute__((ext_vector_type(8))) short s16x8;
typedef __attribute__((ext_vector_type(4))) short s16x4;
typedef __attribute__((ext_vector_type(4))) unsigned int u32x4;

#define AS1 __attribute__((address_space(1)))
#define AS3 __attribute__((address_space(3)))
#define GLOAD_LDS16(g, l) __builtin_amdgcn_global_load_lds( \
    (AS1 void*)(void*)(g), (AS3 void*)(void*)(l), 16, 0, 0)

static __device__ __forceinline__ unsigned short f2bf(float f) {
  unsigned int u = __builtin_bit_cast(unsigned int, f);
  u += 0x7fffu + ((u >> 16) & 1u);   // RNE
  return (unsigned short)(u >> 16);
}

static __device__ __forceinline__ float fexp2(float x) {
  float r;
  asm("v_exp_f32 %0, %1" : "=v"(r) : "v"(x));
  return r;
}

static __device__ __forceinline__ unsigned int cvtpk(float a, float b) {
  unsigned int r;
  asm("v_cvt_pk_bf16_f32 %0, %1, %2" : "=v"(r) : "v"(a), "v"(b));
  return r;
}

static __device__ __forceinline__ f32x4 mfma_bf16(s16x8 a, s16x8 b, f32x4 c) {
  return __builtin_amdgcn_mfma_f32_16x16x32_bf16(a, b, c, 0, 0, 0);
}

// counted waitcnt with compile-time literal
template <int N>
static __device__ __forceinline__ void wait_vm() {
  if constexpr (N >= 8)      asm volatile("s_waitcnt lgkmcnt(0) vmcnt(8)" ::: "memory");
  else if constexpr (N == 6) asm volatile("s_waitcnt lgkmcnt(0) vmcnt(6)" ::: "memory");
  else if constexpr (N == 4) asm volatile("s_waitcnt lgkmcnt(0) vmcnt(4)" ::: "memory");
  else if constexpr (N == 3) asm volatile("s_waitcnt lgkmcnt(0) vmcnt(3)" ::: "memory");
  else if constexpr (N == 2) asm volatile("s_waitcnt lgkmcnt(0) vmcnt(2)" ::: "memory");
  else                       asm volatile("s_waitcnt lgkmcnt(0) vmcnt(0)" ::: "memory");
}

// XCD-bijective swizzle for a 256-block (sub-)grid
static __device__ __forceinline__ int swz256(int bid) {
  return (bid & 7) * 32 + (bid >> 3);
}

// one kernel converts x, w_qkv, w_proj (outputs contiguous in workspace)
__global__ void __launch_bounds__(256) cvt_all(const float* __restrict__ x,
                                               const float* __restrict__ wq,
                                               const float* __restrict__ wp,
                                               unsigned short* __restrict__ out) {
  const int i = blockIdx.x * 256 + threadIdx.x;   // float4 index
  const float* src;
  int j;
  if (i < 2097152) { src = x;  j = i; }
  else if (i < 2883584) { src = wq; j = i - 2097152; }
  else { src = wp; j = i - 2883584; }
  const float4 v = ((const float4*)src)[j];
  ushort4 o;
  o.x = f2bf(v.x); o.y = f2bf(v.y); o.z = f2bf(v.z); o.w = f2bf(v.w);
  ((ushort4*)out)[i] = o;
}

// ---------------------------------------------------------------------------
// 8-phase deep-pipelined GEMM body (round-14 schedule, verified), factored as
// a device function so independent GEMMs can share one dispatch.
// MODE 0: QK epilogue; MODE 1: proj (f32); MODE 2: V^T kv-permuted store.
// ---------------------------------------------------------------------------
template <int MODE, int BMP, int BNP>
static __device__ __forceinline__ void gemm8p_body(
    const unsigned short* __restrict__ Ap, const unsigned short* __restrict__ Bp,
    const float* __restrict__ bias, void* __restrict__ Cout,
    int M, int N, int K, int wgid, unsigned short* lds) {
  constexpr int AHALF = BMP * 4096;   // u16: (BMP*64) rows x 64 cols
  constexpr int BHALF = BNP * 4096;
  constexpr int BBASE = 4 * AHALF;    // A region = 2 buf x 2 half

  const int tid = threadIdx.x;
  const int lane = tid & 63;
  const int wave = tid >> 6;        // 0..7
  const int wr = wave >> 2;         // 0..1  (M half)
  const int wc = wave & 3;          // 0..3  (N quarter)
  const int lr = lane & 15, kg = lane >> 4;

  const int NBM = M >> (BMP == 2 ? 8 : 7);
  const long m0 = (long)(wgid % NBM) * (BMP * 128);
  const long n0 = (long)(wgid / NBM) * (BNP * 128);

#define SA(buf, half, kt) do {                                                  \
    _Pragma("unroll")                                                           \
    for (int i_ = 0; i_ < BMP; ++i_) {                                          \
      const int rh_ = i_ * 64 + wave * 8 + (lane >> 3);                         \
      const int ce_ = ((lane & 7) ^ (lane >> 3)) * 8;                           \
      GLOAD_LDS16(Ap + (m0 + (half) * (BMP * 64) + rh_) * K + (kt) * 64 + ce_,  \
                  &lds[(buf) * 2 * AHALF + (half) * AHALF + i_ * 4096 + wave * 512]); \
    } } while (0)
#define SB(buf, half, kt) do {                                                  \
    _Pragma("unroll")                                                           \
    for (int i_ = 0; i_ < BNP; ++i_) {                                          \
      const int rh_ = i_ * 64 + wave * 8 + (lane >> 3);                         \
      const int ce_ = ((lane & 7) ^ (lane >> 3)) * 8;                           \
      GLOAD_LDS16(Bp + (n0 + (half) * (BNP * 64) + rh_) * K + (kt) * 64 + ce_,  \
                  &lds[BBASE + (buf) * 2 * BHALF + (half) * BHALF + i_ * 4096 + wave * 512]); \
    } } while (0)

#define PH_ENTER() do { __builtin_amdgcn_s_barrier();                           \
    asm volatile("s_waitcnt lgkmcnt(0)" ::: "memory");                          \
    __builtin_amdgcn_sched_barrier(0); } while (0)
#define PH_EXIT() __builtin_amdgcn_s_barrier()
#define PH_EXIT_VM() do { wait_vm<2 * BNP>();                                   \
    __builtin_amdgcn_sched_barrier(0);                                          \
    __builtin_amdgcn_s_barrier(); } while (0)
#define PH_EXIT_VM0() do { wait_vm<0>();                                        \
    __builtin_amdgcn_sched_barrier(0);                                          \
    __builtin_amdgcn_s_barrier(); } while (0)

  f32x4 acc[BMP * 4][BNP * 2] = {};
  s16x8 af[2 * BMP][2], bf0[BNP][2], bf1[BNP][2];

  auto LA = [&](int buf, int qm) {
#pragma unroll
    for (int m = 0; m < 2 * BMP; ++m) {
      const int rh = qm * (BMP * 32) + m * 16 + lr;
      const int ro = (buf * 2 + wr) * AHALF + rh * 64;
#pragma unroll
      for (int ks = 0; ks < 2; ++ks)
        af[m][ks] = *(const s16x8*)
            &lds[ro + (((ks * 64 + kg * 16) ^ ((rh & 7) << 4)) >> 1)];
    }
  };
  auto LB = [&](int buf, int qn, s16x8 (&bf)[BNP][2]) {
#pragma unroll
    for (int n = 0; n < BNP; ++n) {
      const int rh = (wc & 1) * (BNP * 32) + qn * (BNP * 16) + n * 16 + lr;
      const int ro = BBASE + (buf * 2 + (wc >> 1)) * BHALF + rh * 64;
#pragma unroll
      for (int ks = 0; ks < 2; ++ks)
        bf[n][ks] = *(const s16x8*)
            &lds[ro + (((ks * 64 + kg * 16) ^ ((rh & 7) << 4)) >> 1)];
    }
  };
  auto MM = [&](int qm, int qn, s16x8 (&bf)[BNP][2]) {
    __builtin_amdgcn_s_setprio(1);
#pragma unroll
    for (int m = 0; m < 2 * BMP; ++m)
#pragma unroll
      for (int n = 0; n < BNP; ++n)
#pragma unroll
        for (int ks = 0; ks < 2; ++ks)
          acc[qm * 2 * BMP + m][qn * BNP + n] =
              mfma_bf16(af[m][ks], bf[n][ks], acc[qm * 2 * BMP + m][qn * BNP + n]);
    __builtin_amdgcn_s_setprio(0);
  };

  const int nk = K >> 6;      // 64-wide K tiles (16)
  const int nit = nk >> 1;    // 8 iterations, 2 K-tiles each

  SB(0, 0, 0); SB(0, 1, 0);
  SA(0, 0, 0); SA(0, 1, 0);
  SB(1, 0, 1); SB(1, 1, 1);
  wait_vm<2 * BNP>();
  __builtin_amdgcn_sched_barrier(0);
  __builtin_amdgcn_s_barrier();
  __builtin_amdgcn_sched_barrier(0);

  for (int it = 0; it < nit; ++it) {
    const int ta = 2 * it, tb = 2 * it + 1;
    LA(0, 0); LB(0, 0, bf0);
    SA(1, 0, tb);
    PH_ENTER(); MM(0, 0, bf0); PH_EXIT();
    LB(0, 1, bf1);
    SA(1, 1, tb);
    PH_ENTER(); MM(0, 1, bf1); PH_EXIT();
    LA(0, 1);
    if (ta + 2 < nk) SB(0, 0, ta + 2);
    PH_ENTER(); MM(1, 0, bf0); PH_EXIT();
    if (ta + 2 < nk) SB(0, 1, ta + 2);
    PH_ENTER(); MM(1, 1, bf1);
    if (it + 1 < nit) { PH_EXIT_VM(); } else { PH_EXIT_VM0(); }
    LA(1, 0); LB(1, 0, bf0);
    if (ta + 2 < nk) SA(0, 0, ta + 2);
    PH_ENTER(); MM(0, 0, bf0); PH_EXIT();
    LB(1, 1, bf1);
    if (ta + 2 < nk) SA(0, 1, ta + 2);
    PH_ENTER(); MM(0, 1, bf1); PH_EXIT();
    LA(1, 1);
    if (tb + 2 < nk) SB(1, 0, tb + 2);
    PH_ENTER(); MM(1, 0, bf0); PH_EXIT();
    if (tb + 2 < nk) SB(1, 1, tb + 2);
    PH_ENTER(); MM(1, 1, bf1); PH_EXIT_VM();
  }

#pragma unroll
  for (int nt = 0; nt < BNP * 2; ++nt) {
    const long col = n0 + wc * (BNP * 32) + nt * 16 + lr;
    const float bv = (MODE == 2) ? 0.f : bias[col];
#pragma unroll
    for (int mt = 0; mt < BMP * 4; ++mt) {
#pragma unroll
      for (int r = 0; r < 4; ++r) {
        const long row = m0 + wr * (BMP * 64) + mt * 16 + kg * 4 + r;
        if (MODE == 0) {
          float v = acc[mt][nt][r] + bv;
          if (col < EDIM) v *= 0.18033688011112042f;  // 0.125 * log2(e)
          ((unsigned short*)Cout)[row * QKB + col] = f2bf(v);
        } else if (MODE == 1) {
          ((float*)Cout)[row * N + col] = acc[mt][nt][r] + bv;
        } else {
          // V^T store with kv low-5-bit permutation (attn PV b128 layout):
          // s5 = j2*16+g*4+j1 -> p5 = g*8+j2*4+j1
          const float v = acc[mt][nt][r] + bias[row];
          const int base = (int)(col & 2047);
          const int s5 = base & 31;
          const int p5 = ((s5 >> 2) & 3) * 8 + ((s5 >> 4) & 1) * 4 + (s5 & 3);
          const int sperm = (base & ~31) | p5;
          ((unsigned short*)Cout)[((col >> 11) * 1024 + row) * (long)2048 +
                                  sperm] = f2bf(v);
        }
      }
    }
  }
#undef SA
#undef SB
#undef PH_ENTER
#undef PH_EXIT
#undef PH_EXIT_VM
#undef PH_EXIT_VM0
}

// Fused dispatch: blocks 0..255 = QK projection, 256..511 = V^T.
// r21 change: xb-slab co-location — QK's m-slab (wgid%32) and V^T's n-slab
// (wgid/8) of xb satisfy slab/4 == XCD (bid&7) for BOTH halves, so each
// XCD's L2 pins 4 fixed xb slabs (4MB) shared by its QK and V^T blocks.
__global__ void __launch_bounds__(512, 2) gemm_qk_vt(
    const unsigned short* __restrict__ xb, const unsigned short* __restrict__ wqb,
    const float* __restrict__ b_qkv,
    unsigned short* __restrict__ qkb, unsigned short* __restrict__ vTb) {
  extern __shared__ unsigned short lds[];
  const int bid = blockIdx.x;
  if (bid < 256) {
    // m-slab = (bid&7)*4 + ((bid>>3)&3), n = bid>>5   (bijective over 256)
    const int wgid = (bid >> 5) * 32 + (bid & 7) * 4 + ((bid >> 3) & 3);
    gemm8p_body<0, 2, 2>(xb, wqb, b_qkv, qkb, MROWS, QKB, EDIM, wgid, lds);
  } else {
    const int b2 = bid - 256;
    // n-slab = (b2&7)*4 + ((b2>>3)&3), m = b2>>5      (bijective over 256)
    const int wgid = ((b2 & 7) * 4 + ((b2 >> 3) & 3)) * 8 + (b2 >> 5);
    gemm8p_body<2, 1, 2>(wqb + (size_t)2048 * EDIM, xb, b_qkv + 2048, vTb,
                         EDIM, MROWS, EDIM, wgid, lds);
  }
}

__global__ void __launch_bounds__(512, 2) gemm_proj(
    const unsigned short* __restrict__ attb, const unsigned short* __restrict__ wpb,
    const float* __restrict__ b_proj, float* __restrict__ out) {
  extern __shared__ unsigned short lds[];
  gemm8p_body<1, 2, 1>(attb, wpb, b_proj, out, MROWS, EDIM, EDIM,
                       swz256((int)blockIdx.x), lds);
}

// ---------------------------------------------------------------------------
// Flash attention — r20 configuration (verified: 77.9 µs, 0 bank conflicts).
// ---------------------------------------------------------------------------
__global__ void __launch_bounds__(512, 4) attn_fwd(const unsigned short* __restrict__ qk,
                                                   const unsigned short* __restrict__ vT,
                                                   unsigned short* __restrict__ attout) {
  const int L = blockIdx.x;
  const int bh = (L & 7) * 8 + (L >> 6);
  const int qt = (L >> 3) & 7;
  const int b = bh >> 4, h = bh & 15;
  const int q0 = qt * 256;
  const int tid = threadIdx.x, lane = tid & 63, wave = tid >> 6;  // wave 0..7
  const int lr = lane & 15, kg = lane >> 4;

  __shared__ unsigned short Ks[4][4096];   // [slot][k 64][d 64] swizzled
  __shared__ unsigned short Vs[4][4096];   // [slot][d 64][kv 64] permuted+swizzled

  const long rowbase = (long)b * SEQ;

#define ASTAGE(slot, kv0) do {                                                  \
    const int row_ = wave * 8 + (lane >> 3);                                    \
    const int col_ = ((lane & 7) ^ (lane >> 3)) << 3;                           \
    GLOAD_LDS16(qk + (rowbase + (kv0) + row_) * QKB + EDIM + h * HDIM + col_,   \
                &Ks[slot][wave * 512]);                                         \
    GLOAD_LDS16(vT + ((long)bh * HDIM + row_) * SEQ + (kv0) + col_,             \
                &Vs[slot][wave * 512]);                                         \
  } while (0)

#define TILE_BODY(T) do {                                                       \
    const unsigned short* Kb_ = Ks[(T) & 3];                                    \
    const unsigned short* Vb_ = Vs[(T) & 3];                                    \
    f32x4 st[2][4];                                                             \
    __builtin_amdgcn_s_setprio(1);                                              \
    _Pragma("unroll")                                                           \
    for (int ct = 0; ct < 4; ++ct) {                                            \
      const int rb_ = (ct * 16 + lr) * 128;                                     \
      const int sw_ = (lr & 7) << 4;                                            \
      const s16x8 k0_ = *(const s16x8*)&Kb_[(rb_ + ((kg * 16) ^ sw_)) >> 1];    \
      const s16x8 k1_ = *(const s16x8*)&Kb_[(rb_ + ((64 + kg * 16) ^ sw_)) >> 1];\
      _Pragma("unroll")                                                         \
      for (int qs = 0; qs < 2; ++qs) {                                          \
        f32x4 a_ = {};                                                          \
        a_ = mfma_bf16(k0_, qf[qs][0], a_);                                     \
        a_ = mfma_bf16(k1_, qf[qs][1], a_);                                     \
        st[qs][ct] = a_;                                                        \
      }                                                                         \
    }                                                                           \
    __builtin_amdgcn_s_setprio(0);                                              \
    unsigned int pk[2][4][2];                                                   \
    _Pragma("unroll")                                                           \
    for (int qs = 0; qs < 2; ++qs) {                                            \
      f32x4 rv_ = {0.f, 0.f, 0.f, 0.f};                                         \
      _Pragma("unroll")                                                         \
      for (int ct = 0; ct < 4; ++ct) {                                          \
        f32x4 p_;                                                               \
        _Pragma("unroll")                                                       \
        for (int r = 0; r < 4; ++r) p_[r] = fexp2(st[qs][ct][r]);               \
        rv_ += p_;                                                              \
        pk[qs][ct][0] = cvtpk(p_[0], p_[1]);                                    \
        pk[qs][ct][1] = cvtpk(p_[2], p_[3]);                                    \
      }                                                                         \
      l_part[qs] += rv_;                                                        \
    }                                                                           \
    _Pragma("unroll")                                                           \
    for (int kc = 0; kc < 2; ++kc) {                                            \
      s16x8 pa_[2];                                                             \
      _Pragma("unroll")                                                         \
      for (int qs = 0; qs < 2; ++qs) {                                          \
        u32x4 wv_ = {pk[qs][2 * kc][0], pk[qs][2 * kc][1],                      \
                     pk[qs][2 * kc + 1][0], pk[qs][2 * kc + 1][1]};             \
        pa_[qs] = __builtin_bit_cast(s16x8, wv_);                               \
      }                                                                         \
      __builtin_amdgcn_s_setprio(1);                                            \
      _Pragma("unroll")                                                         \
      for (int dt = 0; dt < 4; ++dt) {                                          \
        const int rb_ = (dt * 16 + lr) * 128;                                   \
        const int c0_ = (64 * kc + 16 * kg) ^ ((lr & 7) << 4);                  \
        const s16x8 vf_ = *(const s16x8*)&Vb_[(rb_ + c0_) >> 1];                \
        _Pragma("unroll")                                                       \
        for (int qs = 0; qs < 2; ++qs)                                          \
          o_acc[qs][dt] = mfma_bf16(pa_[qs], vf_, o_acc[qs][dt]);               \
      }                                                                         \
      __builtin_amdgcn_s_setprio(0);                                            \
    }                                                                           \
  } while (0)

  s16x8 qf[2][2];
#pragma unroll
  for (int qs = 0; qs < 2; ++qs) {
    const unsigned short* qp =
        qk + (rowbase + q0 + wave * 32 + qs * 16 + lr) * QKB + h * HDIM + kg * 8;
    qf[qs][0] = *(const s16x8*)qp;
    qf[qs][1] = *(const s16x8*)(qp + 32);
  }

  f32x4 l_part[2] = {{0.f, 0.f, 0.f, 0.f}, {0.f, 0.f, 0.f, 0.f}};
  f32x4 o_acc[2][4] = {};

  // prologue: pair 0 staged and landed
  ASTAGE(0, 0); ASTAGE(1, 64);
  wait_vm<0>();
  __builtin_amdgcn_s_barrier();
  __builtin_amdgcn_sched_barrier(0);

  for (int p = 0; p < 16; ++p) {
    const int t0 = 2 * p;
    if (p + 1 < 16) {   // stage next pair early — latency hidden by 2 bodies
      ASTAGE((t0 + 2) & 3, (t0 + 2) * 64);
      ASTAGE((t0 + 3) & 3, (t0 + 3) * 64);
    }
    TILE_BODY(t0);
    TILE_BODY(t0 + 1);
    wait_vm<0>();       // next pair landed (issued ~2 bodies ago)
    __builtin_amdgcn_s_barrier();
    __builtin_amdgcn_sched_barrier(0);
  }

#pragma unroll
  for (int qs = 0; qs < 2; ++qs) {
    float rs = (l_part[qs][0] + l_part[qs][1]) + (l_part[qs][2] + l_part[qs][3]);
    rs += __shfl_xor(rs, 16, 64);
    rs += __shfl_xor(rs, 32, 64);
#pragma unroll
    for (int r = 0; r < 4; ++r) {
      const float lq = __shfl(rs, kg * 4 + r, 64);
      const float inv = 1.0f / lq;
      const long row = rowbase + q0 + wave * 32 + qs * 16 + kg * 4 + r;
#pragma unroll
      for (int dt = 0; dt < 4; ++dt)
        attout[row * EDIM + h * HDIM + dt * 16 + lr] = f2bf(o_acc[qs][dt][r] * inv);
    }
  }
#undef ASTAGE
#undef TILE_BODY
}

extern "C" void kernel_launch(void* const* d_in, const int* in_sizes, int n_in,
                              void* d_out, int out_size, void* d_ws, size_t ws_size,
                              hipStream_t stream) {
  const float* x      = (const float*)d_in[0];
  const float* w_qkv  = (const float*)d_in[1];
  const float* b_qkv  = (const float*)d_in[2];
  const float* w_proj = (const float*)d_in[3];
  const float* b_proj = (const float*)d_in[4];

  unsigned short* xb   = (unsigned short*)d_ws;              // 8.39M elems
  unsigned short* wqb  = xb   + (size_t)MROWS * EDIM;        // 3.15M
  unsigned short* wpb  = wqb  + (size_t)NQKV * EDIM;         // 1.05M
  unsigned short* qkb  = wpb  + (size_t)EDIM * EDIM;         // 16.8M ([8192][2048])
  unsigned short* attb = qkb  + (size_t)MROWS * QKB;         // 8.39M
  unsigned short* vTb  = attb + (size_t)MROWS * EDIM;        // 8.39M (permuted V^T)

  const int sh22 = 131072;  // max of QK (128KB) / V^T (96KB) paths
  const int sh21 = 98304;   // proj
  hipFuncSetAttribute((const void*)gemm_qk_vt,
                      hipFuncAttributeMaxDynamicSharedMemorySize, sh22);
  hipFuncSetAttribute((const void*)gemm_proj,
                      hipFuncAttributeMaxDynamicSharedMemorySize, sh21);

  cvt_all<<<12288, 256, 0, stream>>>(x, w_qkv, w_proj, xb);

  gemm_qk_vt<<<512, 512, sh22, stream>>>(xb, wqb, b_qkv, qkb, vTb);

  attn_fwd<<<512, 512, 0, stream>>>(qkb, vTb, attb);

  gemm_proj<<<256, 512, sh21, stream>>>(attb, wpb, b_proj, (float*)d_out);
}